// Round 1
// baseline (3952.263 us; speedup 1.0000x reference)
//
#include <hip/hip_runtime.h>
#include <hip/hip_bf16.h>
#include <hip/hip_fp16.h>

typedef long long i64;

__device__ __forceinline__ float ldf(const float* p){ return *p; }
__device__ __forceinline__ float ldf(const __half* p){ return __half2float(*p); }

// Generic strided batched GEMM: C[m,n] = sum_k A[m,k]*B[n,k]
// A[m,k] at A + z1*ab1 + z2*ab2 + m*ams + k*aks   (z = blockIdx.z, z1=z/zdiv, z2=z%zdiv)
// B[n,k] at B + z1*bb1 + z2*bb2 + n*bns + k*bks
// OUT_MODE: 0 = fp32 store; 1 = fp16 store + per-z sum/sumsq atomics into stats;
//           2 = fp32 store with KV_S scatter (m -> chunk q=m>>9, e=m&511; row q*512+n)
template<typename TA, typename TB, int OUT_MODE>
__global__ __launch_bounds__(256) void gemm_any(
    const TA* __restrict__ A, const TB* __restrict__ B,
    void* __restrict__ Cptr, float* __restrict__ stats,
    int M, int N, int K, int zdiv,
    i64 ab1, i64 ab2, i64 ams, i64 aks,
    i64 bb1, i64 bb2, i64 bns, i64 bks,
    i64 cb1, i64 cb2, i64 cms, i64 cns)
{
    __shared__ float As[64][33];
    __shared__ float Bs[64][33];
    const int z = blockIdx.z;
    const int z1 = z / zdiv, z2 = z % zdiv;
    const TA* Ab = A + (i64)z1*ab1 + (i64)z2*ab2;
    const TB* Bb = B + (i64)z1*bb1 + (i64)z2*bb2;
    const i64 cbase = (i64)z1*cb1 + (i64)z2*cb2;
    const int m0 = blockIdx.y * 64;
    const int n0 = blockIdx.x * 64;
    const int tid = threadIdx.x;
    const int tx = tid & 15, ty = tid >> 4;

    float acc[4][4] = {};

    for (int k0 = 0; k0 < K; k0 += 32) {
        if (aks == 1) {
            #pragma unroll
            for (int s = 0; s < 8; ++s) {
                int idx = tid + s*256; int r = idx >> 5, c = idx & 31;
                As[r][c] = ldf(&Ab[(i64)(m0+r)*ams + (k0+c)]);
            }
        } else {
            #pragma unroll
            for (int s = 0; s < 8; ++s) {
                int idx = tid + s*256; int r = idx & 63, c = idx >> 6;
                As[r][c] = ldf(&Ab[(i64)(m0+r)*ams + (i64)(k0+c)*aks]);
            }
        }
        if (bks == 1) {
            #pragma unroll
            for (int s = 0; s < 8; ++s) {
                int idx = tid + s*256; int r = idx >> 5, c = idx & 31;
                Bs[r][c] = ldf(&Bb[(i64)(n0+r)*bns + (k0+c)]);
            }
        } else {
            #pragma unroll
            for (int s = 0; s < 8; ++s) {
                int idx = tid + s*256; int r = idx & 63, c = idx >> 6;
                Bs[r][c] = ldf(&Bb[(i64)(n0+r)*bns + (i64)(k0+c)*bks]);
            }
        }
        __syncthreads();
        #pragma unroll
        for (int kk = 0; kk < 32; ++kk) {
            float a[4], b[4];
            #pragma unroll
            for (int i = 0; i < 4; ++i) a[i] = As[i*16+ty][kk];
            #pragma unroll
            for (int j = 0; j < 4; ++j) b[j] = Bs[j*16+tx][kk];
            #pragma unroll
            for (int i = 0; i < 4; ++i)
                #pragma unroll
                for (int j = 0; j < 4; ++j)
                    acc[i][j] = fmaf(a[i], b[j], acc[i][j]);
        }
        __syncthreads();
    }

    if (OUT_MODE == 0) {
        float* C = (float*)Cptr;
        #pragma unroll
        for (int i = 0; i < 4; ++i)
            #pragma unroll
            for (int j = 0; j < 4; ++j)
                C[cbase + (i64)(m0+i*16+ty)*cms + (i64)(n0+j*16+tx)*cns] = acc[i][j];
    } else if (OUT_MODE == 1) {
        __half* C = (__half*)Cptr;
        float ls = 0.f, lq = 0.f;
        #pragma unroll
        for (int i = 0; i < 4; ++i)
            #pragma unroll
            for (int j = 0; j < 4; ++j) {
                float v = acc[i][j];
                ls += v; lq += v*v;
                C[cbase + (i64)(m0+i*16+ty)*cms + (i64)(n0+j*16+tx)*cns] = __float2half(v);
            }
        #pragma unroll
        for (int off = 32; off; off >>= 1) { ls += __shfl_xor(ls, off); lq += __shfl_xor(lq, off); }
        if ((tid & 63) == 0) { As[0][tid>>6] = ls; Bs[0][tid>>6] = lq; }
        __syncthreads();
        if (tid == 0) {
            float s = As[0][0]+As[0][1]+As[0][2]+As[0][3];
            float q = Bs[0][0]+Bs[0][1]+Bs[0][2]+Bs[0][3];
            atomicAdd(&stats[2*z],   s);
            atomicAdd(&stats[2*z+1], q);
        }
    } else {
        float* C = (float*)Cptr;
        #pragma unroll
        for (int i = 0; i < 4; ++i)
            #pragma unroll
            for (int j = 0; j < 4; ++j) {
                int m = m0 + i*16 + ty, n = n0 + j*16 + tx;
                i64 off = cbase + ((i64)(m >> 9) << 18) + ((i64)n << 9) + (m & 511);
                C[off] = acc[i][j];
            }
    }
}

// Scaled softmax over rows of length 2048 (fp16 in place).
// scale = rsqrt(var+eps) from stats; mean-shift cancels in softmax.
__global__ __launch_bounds__(256) void softmax_rows(
    __half* __restrict__ attn, const float* __restrict__ stats,
    int rows_per_stat, float inv_count)
{
    const int ROWLEN = 2048;
    const int row = blockIdx.x;
    const int sidx = row / rows_per_stat;
    float sm = stats[2*sidx], sq = stats[2*sidx+1];
    float mean = sm * inv_count;
    float var = fmaxf(sq * inv_count - mean*mean, 0.f);
    float scale = rsqrtf(var + 1e-5f);
    __half* rp = attn + (i64)row * ROWLEN;
    const int tid = threadIdx.x;
    float v[8]; float mx = -3.4e38f;
    #pragma unroll
    for (int s = 0; s < 8; ++s) { float x = __half2float(rp[tid + s*256]) * scale; v[s] = x; mx = fmaxf(mx, x); }
    #pragma unroll
    for (int off = 32; off; off >>= 1) mx = fmaxf(mx, __shfl_xor(mx, off));
    __shared__ float red[4];
    if ((tid & 63) == 0) red[tid >> 6] = mx;
    __syncthreads();
    mx = fmaxf(fmaxf(red[0], red[1]), fmaxf(red[2], red[3]));
    float ls = 0.f;
    #pragma unroll
    for (int s = 0; s < 8; ++s) { float e = __expf(v[s] - mx); v[s] = e; ls += e; }
    #pragma unroll
    for (int off = 32; off; off >>= 1) ls += __shfl_xor(ls, off);
    __syncthreads();
    if ((tid & 63) == 0) red[tid >> 6] = ls;
    __syncthreads();
    float inv = 1.f / (red[0] + red[1] + red[2] + red[3]);
    #pragma unroll
    for (int s = 0; s < 8; ++s) rp[tid + s*256] = __float2half(v[s] * inv);
}

extern "C" void kernel_launch(void* const* d_in, const int* in_sizes, int n_in,
                              void* d_out, int out_size, void* d_ws, size_t ws_size,
                              hipStream_t stream)
{
    (void)in_sizes; (void)n_in; (void)out_size;
    const int Bb = 4, Ntok = 512, E = 512, Hh = 8, Cc = 2048, Dd = 64, M4 = 2048;
    const float* emb[4] = {(const float*)d_in[0], (const float*)d_in[1],
                           (const float*)d_in[2], (const float*)d_in[3]};
    const float* embC = (const float*)d_in[4];
    const float* Wq[4] = {(const float*)d_in[5], (const float*)d_in[6],
                          (const float*)d_in[7], (const float*)d_in[8]};
    const float* Wk  = (const float*)d_in[9];
    const float* Wv  = (const float*)d_in[10];
    const float* WqC = (const float*)d_in[11];
    const float* WkC = (const float*)d_in[12];
    const float* WvC = (const float*)d_in[13];
    const float* Wo[4] = {(const float*)d_in[14], (const float*)d_in[15],
                          (const float*)d_in[16], (const float*)d_in[17]};
    float* out = (float*)d_out;

    char* ws = (char*)d_ws;
    const size_t MB = 1024*1024;
    if (ws_size < 128*MB + 512) return;  // need 128MB + stats
    float*  QC    = (float*)(ws + 0);
    float*  KC    = (float*)(ws + 16*MB);
    float*  VC    = (float*)(ws + 32*MB);
    __half* attnC = (__half*)(ws + 48*MB);   // 32MB
    float*  KVS   = (float*)(ws + 80*MB);
    float*  Km    = (float*)(ws + 96*MB);
    float*  Vm    = (float*)(ws + 112*MB);
    float*  Qb    = (float*)(ws + 0);        // reuse QC region (dead by then)
    float*  ctx   = (float*)(ws + 4*MB);
    __half* attnS = (__half*)(ws + 8*MB);    // 64MB, reuses KC/VC/attnC regions
    float*  stats = (float*)(ws + 128*MB);   // [0..7] channel, [64..127] spatial
    float*  statsS = stats + 64;

    hipMemsetAsync(stats, 0, 512, stream);

    // ---- channel projections: QC/KC/VC = embC @ W^T  (M=512, N=2048, K=2048) ----
    {
        dim3 g(Cc/64, Ntok/64, Bb);
        gemm_any<float,float,0><<<g,256,0,stream>>>(embC, WqC, QC, nullptr,
            Ntok, Cc, Cc, 1,
            (i64)Ntok*Cc, 0, Cc, 1,   0, 0, Cc, 1,   (i64)Ntok*Cc, 0, Cc, 1);
        gemm_any<float,float,0><<<g,256,0,stream>>>(embC, WkC, KC, nullptr,
            Ntok, Cc, Cc, 1,
            (i64)Ntok*Cc, 0, Cc, 1,   0, 0, Cc, 1,   (i64)Ntok*Cc, 0, Cc, 1);
        gemm_any<float,float,0><<<g,256,0,stream>>>(embC, WvC, VC, nullptr,
            Ntok, Cc, Cc, 1,
            (i64)Ntok*Cc, 0, Cc, 1,   0, 0, Cc, 1,   (i64)Ntok*Cc, 0, Cc, 1);
    }
    // ---- attn_c[c,d] = sum_n QC[n,c] KC[n,d]  (TN, M=N=2048, K=512) + stats ----
    {
        dim3 g(Cc/64, Cc/64, Bb);
        gemm_any<float,float,1><<<g,256,0,stream>>>(QC, KC, attnC, stats,
            Cc, Cc, Ntok, 1,
            (i64)Ntok*Cc, 0, 1, Cc,   (i64)Ntok*Cc, 0, 1, Cc,   (i64)Cc*Cc, 0, Cc, 1);
    }
    // ---- channel softmax (scale only; mean cancels) ----
    softmax_rows<<<dim3(Bb*Cc),256,0,stream>>>(attnC, stats, Cc, 1.f/((float)Cc*(float)Cc));
    // ---- ctx_c = sim @ VC^T, scattered into KV_S[b, q*512+n, e] ----
    {
        dim3 g(Ntok/64, Cc/64, Bb);
        gemm_any<__half,float,2><<<g,256,0,stream>>>(attnC, VC, KVS, nullptr,
            Cc, Ntok, Cc, 1,
            (i64)Cc*Cc, 0, Cc, 1,   (i64)Ntok*Cc, 0, Cc, 1,   (i64)M4*E, 0, 0, 0);
    }
    // ---- K, V = KV_S @ W^T (M=2048, N=512, K=512) ----
    {
        dim3 g(E/64, M4/64, Bb);
        gemm_any<float,float,0><<<g,256,0,stream>>>(KVS, Wk, Km, nullptr,
            M4, E, E, 1,
            (i64)M4*E, 0, E, 1,   0, 0, E, 1,   (i64)M4*E, 0, E, 1);
        gemm_any<float,float,0><<<g,256,0,stream>>>(KVS, Wv, Vm, nullptr,
            M4, E, E, 1,
            (i64)M4*E, 0, E, 1,   0, 0, E, 1,   (i64)M4*E, 0, E, 1);
    }
    // ---- 4 spatial streams ----
    for (int s = 0; s < 4; ++s) {
        hipMemsetAsync(statsS, 0, 256, stream);
        // Q = emb @ Wq^T
        {
            dim3 g(E/64, Ntok/64, Bb);
            gemm_any<float,float,0><<<g,256,0,stream>>>(emb[s], Wq[s], Qb, nullptr,
                Ntok, E, E, 1,
                (i64)Ntok*E, 0, E, 1,   0, 0, E, 1,   (i64)Ntok*E, 0, E, 1);
        }
        // scores[z=b*H+h][n][m] = Q[b,n,hD+k]*K[b,m,hD+k], K=64, + stats
        {
            dim3 g(M4/64, Ntok/64, Bb*Hh);
            gemm_any<float,float,1><<<g,256,0,stream>>>(Qb, Km, attnS, statsS,
                Ntok, M4, Dd, Hh,
                (i64)Ntok*E, (i64)Dd, E, 1,
                (i64)M4*E,   (i64)Dd, E, 1,
                (i64)Hh*Ntok*M4, (i64)Ntok*M4, M4, 1);
        }
        softmax_rows<<<dim3(Bb*Hh*Ntok),256,0,stream>>>(attnS, statsS, Ntok, 1.f/((float)Ntok*(float)M4));
        // ctx[b,n,hD+d] = sum_m sim[z,n,m] V[b,m,hD+d]  (M=512, N=64, K=2048)
        {
            dim3 g(Dd/64, Ntok/64, Bb*Hh);
            gemm_any<__half,float,0><<<g,256,0,stream>>>(attnS, Vm, ctx, nullptr,
                Ntok, Dd, M4, Hh,
                (i64)Hh*Ntok*M4, (i64)Ntok*M4, M4, 1,
                (i64)M4*E, (i64)Dd, 1, E,
                (i64)Ntok*E, (i64)Dd, E, 1);
        }
        // out_s = ctx @ Wo^T
        {
            dim3 g(E/64, Ntok/64, Bb);
            gemm_any<float,float,0><<<g,256,0,stream>>>(ctx, Wo[s], out + (i64)s*Bb*Ntok*E, nullptr,
                Ntok, E, E, 1,
                (i64)Ntok*E, 0, E, 1,   0, 0, E, 1,   (i64)Ntok*E, 0, E, 1);
        }
    }
}

// Round 2
// 1869.721 us; speedup vs baseline: 2.1138x; 2.1138x over previous
//
#include <hip/hip_runtime.h>
#include <hip/hip_bf16.h>
#include <hip/hip_fp16.h>

typedef long long i64;
typedef __attribute__((ext_vector_type(8))) short bf16x8;
typedef __attribute__((ext_vector_type(4))) float f32x4;

#define MFMA_BF16 __builtin_amdgcn_mfma_f32_16x16x32_bf16

__device__ __forceinline__ void ld4(const float* p, float v[4]){
    const float4 t = *(const float4*)p;
    v[0]=t.x; v[1]=t.y; v[2]=t.z; v[3]=t.w;
}
__device__ __forceinline__ void ld4(const __half* p, float v[4]){
    const __half2* q = (const __half2*)p;
    __half2 a = q[0], b = q[1];
    v[0]=__low2float(a); v[1]=__high2float(a);
    v[2]=__low2float(b); v[3]=__high2float(b);
}
// fp32 -> bf16 hi (truncate) + bf16 lo (truncated residual). a ≈ hi + lo, |err| ~ 2^-16 |a|
__device__ __forceinline__ void split1(float x, ushort& h, ushort& l){
    unsigned b = __float_as_uint(x);
    h = (ushort)(b >> 16);
    float hf = __uint_as_float(b & 0xFFFF0000u);
    float lf = x - hf;                       // exact (Sterbenz-ish: top 8 mantissa bits removed)
    l = (ushort)(__float_as_uint(lf) >> 16);
}

// Stage a TR x 32 tile (rows r0.., k-cols k0..k0+31) into hi/lo LDS planes.
// ks==1: k-contiguous (vec4 along k). else: rs==1, r-contiguous (vec4 along r).
template<int TR, typename T>
__device__ __forceinline__ void stage_tile(const T* __restrict__ base, i64 rs, i64 ks,
                                           int r0, int k0,
                                           ushort (*__restrict__ Hh)[40],
                                           ushort (*__restrict__ Ll)[40], int tid)
{
    if (ks == 1) {
        #pragma unroll
        for (int s = 0; s < TR/32; ++s) {
            int v = tid + s*256;          // v < TR*8
            int r = v >> 3, c4 = v & 7;   // 8 vec4 per row
            float vals[4]; ld4(&base[(i64)(r0+r)*rs + (k0 + c4*4)], vals);
            ushort h[4], l[4];
            #pragma unroll
            for (int t = 0; t < 4; ++t) split1(vals[t], h[t], l[t]);
            *(ushort4*)&Hh[r][c4*4] = make_ushort4(h[0],h[1],h[2],h[3]);
            *(ushort4*)&Ll[r][c4*4] = make_ushort4(l[0],l[1],l[2],l[3]);
        }
    } else {
        constexpr int LMV = (TR==128) ? 5 : 4;   // log2(TR/4)
        #pragma unroll
        for (int s = 0; s < TR/32; ++s) {
            int v = tid + s*256;
            int rv = v & (TR/4 - 1), k = v >> LMV;   // k in 0..31
            float vals[4]; ld4(&base[(i64)(k0+k)*ks + (i64)(r0 + rv*4)*rs], vals);
            #pragma unroll
            for (int t = 0; t < 4; ++t) {
                ushort h, l; split1(vals[t], h, l);
                Hh[rv*4+t][k] = h; Ll[rv*4+t][k] = l;
            }
        }
    }
}

// Strided batched GEMM on MFMA, bf16x3 error-compensated split (fp32-equivalent).
// C[m,n] = sum_k A[m,k]*B[n,k].  z = blockIdx.z, z1=z/zdiv, z2=z%zdiv.
// OUT_MODE: 0 fp32 store; 1 fp16 store + per-z sum/sumsq atomics; 2 fp32 KV_S scatter.
template<int TM, int TN, typename TA, int OUT_MODE>
__global__ __launch_bounds__(256) void gemm_mfma(
    const TA* __restrict__ A, const float* __restrict__ B,
    void* __restrict__ Cptr, float* __restrict__ stats,
    int K, int zdiv,
    i64 ab1, i64 ab2, i64 ams, i64 aks,
    i64 bb1, i64 bb2, i64 bns, i64 bks,
    i64 cb1, i64 cb2, i64 cms, i64 cns)
{
    constexpr int FM = TM/32, FN = TN/32;   // 16x16 frags per wave (2x2 wave grid)
    __shared__ ushort Ah[TM][40], Al[TM][40];   // 80B row stride: 16B-aligned rows,
    __shared__ ushort Bh[TN][40], Bl[TN][40];   // bank-uniform for b128 frag reads
    __shared__ float sred[4], qred[4];

    const int z = blockIdx.z;
    const int z1 = z / zdiv, z2 = z % zdiv;
    const TA* Ab = A + (i64)z1*ab1 + (i64)z2*ab2;
    const float* Bb = B + (i64)z1*bb1 + (i64)z2*bb2;
    const i64 cbase = (i64)z1*cb1 + (i64)z2*cb2;
    const int m0 = blockIdx.y * TM;
    const int n0 = blockIdx.x * TN;
    const int tid = threadIdx.x;
    const int lane = tid & 63;
    const int wid = tid >> 6;
    const int wm = wid >> 1, wn = wid & 1;    // 2x2 waves
    const int fr = lane & 15, kc = lane >> 4; // frag row / k-chunk (and output row group)

    f32x4 acc[FM][FN];
    #pragma unroll
    for (int i = 0; i < FM; ++i)
        #pragma unroll
        for (int j = 0; j < FN; ++j)
            acc[i][j] = (f32x4){0.f,0.f,0.f,0.f};

    for (int k0 = 0; k0 < K; k0 += 32) {
        stage_tile<TM>(Ab, ams, aks, m0, k0, Ah, Al, tid);
        stage_tile<TN>(Bb, bns, bks, n0, k0, Bh, Bl, tid);
        __syncthreads();

        bf16x8 ah[FM], al[FM], bh[FN], bl[FN];
        #pragma unroll
        for (int i = 0; i < FM; ++i) {
            int row = wm*(TM/2) + i*16 + fr;
            ah[i] = *(const bf16x8*)&Ah[row][kc*8];
            al[i] = *(const bf16x8*)&Al[row][kc*8];
        }
        #pragma unroll
        for (int j = 0; j < FN; ++j) {
            int row = wn*(TN/2) + j*16 + fr;
            bh[j] = *(const bf16x8*)&Bh[row][kc*8];
            bl[j] = *(const bf16x8*)&Bl[row][kc*8];
        }
        #pragma unroll
        for (int i = 0; i < FM; ++i)
            #pragma unroll
            for (int j = 0; j < FN; ++j) {
                acc[i][j] = MFMA_BF16(ah[i], bh[j], acc[i][j], 0, 0, 0);
                acc[i][j] = MFMA_BF16(ah[i], bl[j], acc[i][j], 0, 0, 0);
                acc[i][j] = MFMA_BF16(al[i], bh[j], acc[i][j], 0, 0, 0);
            }
        __syncthreads();
    }

    // D mapping (m89-verified): col = lane&15, row = (lane>>4)*4 + reg
    if (OUT_MODE == 0) {
        float* C = (float*)Cptr;
        #pragma unroll
        for (int i = 0; i < FM; ++i)
            #pragma unroll
            for (int j = 0; j < FN; ++j)
                #pragma unroll
                for (int r = 0; r < 4; ++r) {
                    int m = m0 + wm*(TM/2) + i*16 + kc*4 + r;
                    int n = n0 + wn*(TN/2) + j*16 + fr;
                    C[cbase + (i64)m*cms + (i64)n*cns] = acc[i][j][r];
                }
    } else if (OUT_MODE == 1) {
        __half* C = (__half*)Cptr;
        float ls = 0.f, lq = 0.f;
        #pragma unroll
        for (int i = 0; i < FM; ++i)
            #pragma unroll
            for (int j = 0; j < FN; ++j)
                #pragma unroll
                for (int r = 0; r < 4; ++r) {
                    int m = m0 + wm*(TM/2) + i*16 + kc*4 + r;
                    int n = n0 + wn*(TN/2) + j*16 + fr;
                    float v = acc[i][j][r];
                    ls += v; lq += v*v;
                    C[cbase + (i64)m*cms + (i64)n*cns] = __float2half(v);
                }
        #pragma unroll
        for (int off = 32; off; off >>= 1) { ls += __shfl_xor(ls, off); lq += __shfl_xor(lq, off); }
        if (lane == 0) { sred[wid] = ls; qred[wid] = lq; }
        __syncthreads();
        if (tid == 0) {
            atomicAdd(&stats[2*z],   sred[0]+sred[1]+sred[2]+sred[3]);
            atomicAdd(&stats[2*z+1], qred[0]+qred[1]+qred[2]+qred[3]);
        }
    } else {
        float* C = (float*)Cptr;
        #pragma unroll
        for (int i = 0; i < FM; ++i)
            #pragma unroll
            for (int j = 0; j < FN; ++j)
                #pragma unroll
                for (int r = 0; r < 4; ++r) {
                    int m = m0 + wm*(TM/2) + i*16 + kc*4 + r;
                    int n = n0 + wn*(TN/2) + j*16 + fr;
                    i64 off = cbase + ((i64)(m >> 9) << 18) + ((i64)n << 9) + (m & 511);
                    C[off] = acc[i][j][r];
                }
    }
}

// Scaled softmax over rows of length 2048 (fp16 in place).
// scale = rsqrt(var+eps); InstanceNorm mean-shift cancels in softmax.
__global__ __launch_bounds__(256) void softmax_rows(
    __half* __restrict__ attn, const float* __restrict__ stats,
    int rows_per_stat, float inv_count)
{
    const int ROWLEN = 2048;
    const int row = blockIdx.x;
    const int sidx = row / rows_per_stat;
    float sm = stats[2*sidx], sq = stats[2*sidx+1];
    float mean = sm * inv_count;
    float var = fmaxf(sq * inv_count - mean*mean, 0.f);
    float scale = rsqrtf(var + 1e-5f);
    __half* rp = attn + (i64)row * ROWLEN;
    const int tid = threadIdx.x;
    float v[8]; float mx = -3.4e38f;
    #pragma unroll
    for (int s = 0; s < 8; ++s) { float x = __half2float(rp[tid + s*256]) * scale; v[s] = x; mx = fmaxf(mx, x); }
    #pragma unroll
    for (int off = 32; off; off >>= 1) mx = fmaxf(mx, __shfl_xor(mx, off));
    __shared__ float red[4];
    if ((tid & 63) == 0) red[tid >> 6] = mx;
    __syncthreads();
    mx = fmaxf(fmaxf(red[0], red[1]), fmaxf(red[2], red[3]));
    float ls = 0.f;
    #pragma unroll
    for (int s = 0; s < 8; ++s) { float e = __expf(v[s] - mx); v[s] = e; ls += e; }
    #pragma unroll
    for (int off = 32; off; off >>= 1) ls += __shfl_xor(ls, off);
    __syncthreads();
    if ((tid & 63) == 0) red[tid >> 6] = ls;
    __syncthreads();
    float inv = 1.f / (red[0] + red[1] + red[2] + red[3]);
    #pragma unroll
    for (int s = 0; s < 8; ++s) rp[tid + s*256] = __float2half(v[s] * inv);
}

extern "C" void kernel_launch(void* const* d_in, const int* in_sizes, int n_in,
                              void* d_out, int out_size, void* d_ws, size_t ws_size,
                              hipStream_t stream)
{
    (void)in_sizes; (void)n_in; (void)out_size;
    const int Bb = 4, Ntok = 512, E = 512, Hh = 8, Cc = 2048, Dd = 64, M4 = 2048;
    const float* emb[4] = {(const float*)d_in[0], (const float*)d_in[1],
                           (const float*)d_in[2], (const float*)d_in[3]};
    const float* embC = (const float*)d_in[4];
    const float* Wq[4] = {(const float*)d_in[5], (const float*)d_in[6],
                          (const float*)d_in[7], (const float*)d_in[8]};
    const float* Wk  = (const float*)d_in[9];
    const float* Wv  = (const float*)d_in[10];
    const float* WqC = (const float*)d_in[11];
    const float* WkC = (const float*)d_in[12];
    const float* WvC = (const float*)d_in[13];
    const float* Wo[4] = {(const float*)d_in[14], (const float*)d_in[15],
                          (const float*)d_in[16], (const float*)d_in[17]};
    float* out = (float*)d_out;

    char* ws = (char*)d_ws;
    const size_t MB = 1024*1024;
    if (ws_size < 128*MB + 512) return;
    float*  QC    = (float*)(ws + 0);
    float*  KC    = (float*)(ws + 16*MB);
    float*  VC    = (float*)(ws + 32*MB);
    __half* attnC = (__half*)(ws + 48*MB);   // 32MB
    float*  KVS   = (float*)(ws + 80*MB);
    float*  Km    = (float*)(ws + 96*MB);
    float*  Vm    = (float*)(ws + 112*MB);
    float*  Qb    = (float*)(ws + 0);        // reuse (QC dead)
    float*  ctx   = (float*)(ws + 4*MB);
    __half* attnS = (__half*)(ws + 8*MB);    // 64MB (KC/VC/attnC dead)
    float*  stats = (float*)(ws + 128*MB);
    float*  statsS = stats + 64;

    hipMemsetAsync(stats, 0, 512, stream);

    // channel projections: QC/KC/VC = embC @ W^T   M=512 N=2048 K=2048
    {
        dim3 g(Cc/128, Ntok/128, Bb);
        gemm_mfma<128,128,float,0><<<g,256,0,stream>>>(embC, WqC, QC, nullptr, Cc, 1,
            (i64)Ntok*Cc, 0, Cc, 1,   0, 0, Cc, 1,   (i64)Ntok*Cc, 0, Cc, 1);
        gemm_mfma<128,128,float,0><<<g,256,0,stream>>>(embC, WkC, KC, nullptr, Cc, 1,
            (i64)Ntok*Cc, 0, Cc, 1,   0, 0, Cc, 1,   (i64)Ntok*Cc, 0, Cc, 1);
        gemm_mfma<128,128,float,0><<<g,256,0,stream>>>(embC, WvC, VC, nullptr, Cc, 1,
            (i64)Ntok*Cc, 0, Cc, 1,   0, 0, Cc, 1,   (i64)Ntok*Cc, 0, Cc, 1);
    }
    // attn_c[c,d] = sum_n QC[n,c] KC[n,d]  (both transposed) + stats
    {
        dim3 g(Cc/128, Cc/128, Bb);
        gemm_mfma<128,128,float,1><<<g,256,0,stream>>>(QC, KC, attnC, stats, Ntok, 1,
            (i64)Ntok*Cc, 0, 1, Cc,   (i64)Ntok*Cc, 0, 1, Cc,   (i64)Cc*Cc, 0, Cc, 1);
    }
    softmax_rows<<<dim3(Bb*Cc),256,0,stream>>>(attnC, stats, Cc, 1.f/((float)Cc*(float)Cc));
    // ctx_c = sim @ VC^T, scatter into KV_S
    {
        dim3 g(Ntok/128, Cc/128, Bb);
        gemm_mfma<128,128,__half,2><<<g,256,0,stream>>>(attnC, VC, KVS, nullptr, Cc, 1,
            (i64)Cc*Cc, 0, Cc, 1,   (i64)Ntok*Cc, 0, Cc, 1,   (i64)M4*E, 0, 0, 0);
    }
    // K, V = KV_S @ W^T   M=2048 N=512 K=512
    {
        dim3 g(E/128, M4/128, Bb);
        gemm_mfma<128,128,float,0><<<g,256,0,stream>>>(KVS, Wk, Km, nullptr, E, 1,
            (i64)M4*E, 0, E, 1,   0, 0, E, 1,   (i64)M4*E, 0, E, 1);
        gemm_mfma<128,128,float,0><<<g,256,0,stream>>>(KVS, Wv, Vm, nullptr, E, 1,
            (i64)M4*E, 0, E, 1,   0, 0, E, 1,   (i64)M4*E, 0, E, 1);
    }
    // 4 spatial streams
    for (int s = 0; s < 4; ++s) {
        hipMemsetAsync(statsS, 0, 256, stream);
        // Q = emb @ Wq^T  (512x512x512)
        {
            dim3 g(E/64, Ntok/64, Bb);
            gemm_mfma<64,64,float,0><<<g,256,0,stream>>>(emb[s], Wq[s], Qb, nullptr, E, 1,
                (i64)Ntok*E, 0, E, 1,   0, 0, E, 1,   (i64)Ntok*E, 0, E, 1);
        }
        // scores[z=b*H+h] = Q·K^T per head, K=64, + stats
        {
            dim3 g(M4/128, Ntok/128, Bb*Hh);
            gemm_mfma<128,128,float,1><<<g,256,0,stream>>>(Qb, Km, attnS, statsS, Dd, Hh,
                (i64)Ntok*E, (i64)Dd, E, 1,
                (i64)M4*E,   (i64)Dd, E, 1,
                (i64)Hh*Ntok*M4, (i64)Ntok*M4, M4, 1);
        }
        softmax_rows<<<dim3(Bb*Hh*Ntok),256,0,stream>>>(attnS, statsS, Ntok, 1.f/((float)Ntok*(float)M4));
        // ctx = sim @ V per head  (M=512, N=64, K=2048; V k-strided)
        {
            dim3 g(Dd/64, Ntok/64, Bb*Hh);
            gemm_mfma<64,64,__half,0><<<g,256,0,stream>>>(attnS, Vm, ctx, nullptr, M4, Hh,
                (i64)Hh*Ntok*M4, (i64)Ntok*M4, M4, 1,
                (i64)M4*E, (i64)Dd, 1, E,
                (i64)Ntok*E, (i64)Dd, E, 1);
        }
        // out_s = ctx @ Wo^T
        {
            dim3 g(E/64, Ntok/64, Bb);
            gemm_mfma<64,64,float,0><<<g,256,0,stream>>>(ctx, Wo[s], out + (i64)s*Bb*Ntok*E, nullptr, E, 1,
                (i64)Ntok*E, 0, E, 1,   0, 0, E, 1,   (i64)Ntok*E, 0, E, 1);
        }
    }
}

// Round 3
// 852.979 us; speedup vs baseline: 4.6335x; 2.1920x over previous
//
#include <hip/hip_runtime.h>
#include <hip/hip_bf16.h>
#include <hip/hip_fp16.h>

typedef long long i64;
typedef __attribute__((ext_vector_type(8))) short bf16x8;
typedef __attribute__((ext_vector_type(4))) float f32x4;

#define MFMA_BF16 __builtin_amdgcn_mfma_f32_16x16x32_bf16

__device__ __forceinline__ float ldf1(const float* p){ return *p; }
__device__ __forceinline__ float ldf1(const __half* p){ return __half2float(*p); }
__device__ __forceinline__ void ld4(const float* p, float v[4]){
    const float4 t = *(const float4*)p;
    v[0]=t.x; v[1]=t.y; v[2]=t.z; v[3]=t.w;
}
__device__ __forceinline__ void ld4(const __half* p, float v[4]){
    const __half2* q = (const __half2*)p;
    __half2 a = q[0], b = q[1];
    v[0]=__low2float(a); v[1]=__high2float(a);
    v[2]=__low2float(b); v[3]=__high2float(b);
}
// fp32 -> bf16 hi (truncate) + bf16 lo (residual). a ~= hi + lo, |err| ~ 2^-16 |a|
__device__ __forceinline__ void split1(float x, ushort& h, ushort& l){
    unsigned b = __float_as_uint(x);
    h = (ushort)(b >> 16);
    float hf = __uint_as_float(b & 0xFFFF0000u);
    float lf = x - hf;
    l = (ushort)(__float_as_uint(lf) >> 16);
}
// per-row XOR swizzle of 4-ushort groups (even -> preserves b128 pairs & 16B align)
__device__ __forceinline__ int sw2of(int r){ return ((r ^ (r >> 3)) & 3) << 1; }

__device__ __forceinline__ bf16x8 frag_read(const ushort (*P)[40], int row, int kc){
    return *(const bf16x8*)&P[row][((kc*2) ^ sw2of(row)) * 4];
}

// stage TR x 32 tile, k-contiguous source (aks==1): vec4 along k
template<int TR, typename T>
__device__ __forceinline__ void stage_kc(const T* __restrict__ base, i64 rs,
                                         int r0, int k0,
                                         ushort (*__restrict__ Hh)[40],
                                         ushort (*__restrict__ Ll)[40], int tid)
{
    #pragma unroll
    for (int s = 0; s < TR/32; ++s) {
        int v = tid + s*256;
        int r = v >> 3, c4 = v & 7;
        float vals[4]; ld4(&base[(i64)(r0+r)*rs + (k0 + c4*4)], vals);
        ushort h[4], l[4];
        #pragma unroll
        for (int t = 0; t < 4; ++t) split1(vals[t], h[t], l[t]);
        int pc = (c4 ^ sw2of(r)) * 4;
        *(ushort4*)&Hh[r][pc] = make_ushort4(h[0],h[1],h[2],h[3]);
        *(ushort4*)&Ll[r][pc] = make_ushort4(l[0],l[1],l[2],l[3]);
    }
}
// stage TR x 32 tile, strided-k source (rs==1 row-contiguous): thread owns (r, k4)
template<int TR, typename T>
__device__ __forceinline__ void stage_st(const T* __restrict__ base, i64 rs, i64 ks,
                                         int r0, int k0,
                                         ushort (*__restrict__ Hh)[40],
                                         ushort (*__restrict__ Ll)[40], int tid)
{
    constexpr int LTR = (TR==128) ? 7 : 6;
    #pragma unroll
    for (int s = 0; s < TR/32; ++s) {
        int v = tid + s*256;
        int r = v & (TR-1), k4 = v >> LTR;
        ushort h[4], l[4];
        #pragma unroll
        for (int kk = 0; kk < 4; ++kk) {
            float x = ldf1(&base[(i64)(k0 + k4*4 + kk)*ks + (i64)(r0 + r)*rs]);
            split1(x, h[kk], l[kk]);
        }
        int pc = (k4 ^ sw2of(r)) * 4;
        *(ushort4*)&Hh[r][pc] = make_ushort4(h[0],h[1],h[2],h[3]);
        *(ushort4*)&Ll[r][pc] = make_ushort4(l[0],l[1],l[2],l[3]);
    }
}

struct P4 { const void* p[4]; };

// Strided batched GEMM on MFMA, bf16x3 split. C[m,n] = sum_k A[m,k]*B[n,k].
// z = blockIdx.z, z1=z/zdiv, z2=z%zdiv; base pointers indexed by z1.
// OUT_MODE: 0 fp32; 1 fp16 + per-z sum/sumsq atomics; 2 fp32 KV_S scatter.
template<int TM, int TN, typename TA, int OUT_MODE>
__global__ __launch_bounds__(256) void gemm_mfma(
    P4 Ap, P4 Bp, P4 Cp, float* __restrict__ stats,
    int K, int zdiv,
    i64 ab2, i64 ams, i64 aks,
    i64 bb2, i64 bns, i64 bks,
    i64 cb2, i64 cms, i64 cns)
{
    constexpr int FM = TM/32, FN = TN/32;
    __shared__ ushort Ah[TM][40], Al[TM][40];
    __shared__ ushort Bh[TN][40], Bl[TN][40];
    __shared__ float sred[4], qred[4];

    const int z = blockIdx.z;
    const int z1 = z / zdiv, z2 = z % zdiv;
    const TA* Ab = (const TA*)Ap.p[z1] + (i64)z2*ab2;
    const float* Bb = (const float*)Bp.p[z1] + (i64)z2*bb2;
    const i64 cbase = (i64)z2*cb2;
    const int m0 = blockIdx.y * TM;
    const int n0 = blockIdx.x * TN;
    const int tid = threadIdx.x;
    const int lane = tid & 63;
    const int wid = tid >> 6;
    const int wm = wid >> 1, wn = wid & 1;
    const int fr = lane & 15, kc = lane >> 4;

    f32x4 acc[FM][FN];
    #pragma unroll
    for (int i = 0; i < FM; ++i)
        #pragma unroll
        for (int j = 0; j < FN; ++j)
            acc[i][j] = (f32x4){0.f,0.f,0.f,0.f};

    for (int k0 = 0; k0 < K; k0 += 32) {
        if (aks == 1) stage_kc<TM>(Ab, ams, m0, k0, Ah, Al, tid);
        else          stage_st<TM>(Ab, ams, aks, m0, k0, Ah, Al, tid);
        if (bks == 1) stage_kc<TN>(Bb, bns, n0, k0, Bh, Bl, tid);
        else          stage_st<TN>(Bb, bns, bks, n0, k0, Bh, Bl, tid);
        __syncthreads();

        bf16x8 ah[FM], al[FM], bh[FN], bl[FN];
        #pragma unroll
        for (int i = 0; i < FM; ++i) {
            int row = wm*(TM/2) + i*16 + fr;
            ah[i] = frag_read(Ah, row, kc);
            al[i] = frag_read(Al, row, kc);
        }
        #pragma unroll
        for (int j = 0; j < FN; ++j) {
            int row = wn*(TN/2) + j*16 + fr;
            bh[j] = frag_read(Bh, row, kc);
            bl[j] = frag_read(Bl, row, kc);
        }
        #pragma unroll
        for (int i = 0; i < FM; ++i)
            #pragma unroll
            for (int j = 0; j < FN; ++j) {
                acc[i][j] = MFMA_BF16(ah[i], bh[j], acc[i][j], 0, 0, 0);
                acc[i][j] = MFMA_BF16(ah[i], bl[j], acc[i][j], 0, 0, 0);
                acc[i][j] = MFMA_BF16(al[i], bh[j], acc[i][j], 0, 0, 0);
            }
        __syncthreads();
    }

    if (OUT_MODE == 0) {
        float* C = (float*)Cp.p[z1];
        #pragma unroll
        for (int i = 0; i < FM; ++i)
            #pragma unroll
            for (int j = 0; j < FN; ++j)
                #pragma unroll
                for (int r = 0; r < 4; ++r) {
                    int m = m0 + wm*(TM/2) + i*16 + kc*4 + r;
                    int n = n0 + wn*(TN/2) + j*16 + fr;
                    C[cbase + (i64)m*cms + (i64)n*cns] = acc[i][j][r];
                }
    } else if (OUT_MODE == 1) {
        __half* C = (__half*)Cp.p[z1];
        float ls = 0.f, lq = 0.f;
        #pragma unroll
        for (int i = 0; i < FM; ++i)
            #pragma unroll
            for (int j = 0; j < FN; ++j)
                #pragma unroll
                for (int r = 0; r < 4; ++r) {
                    int m = m0 + wm*(TM/2) + i*16 + kc*4 + r;
                    int n = n0 + wn*(TN/2) + j*16 + fr;
                    float v = acc[i][j][r];
                    ls += v; lq += v*v;
                    C[cbase + (i64)m*cms + (i64)n*cns] = __float2half(v);
                }
        #pragma unroll
        for (int off = 32; off; off >>= 1) { ls += __shfl_xor(ls, off); lq += __shfl_xor(lq, off); }
        if (lane == 0) { sred[wid] = ls; qred[wid] = lq; }
        __syncthreads();
        if (tid == 0) {
            atomicAdd(&stats[2*z],   sred[0]+sred[1]+sred[2]+sred[3]);
            atomicAdd(&stats[2*z+1], qred[0]+qred[1]+qred[2]+qred[3]);
        }
    } else {
        float* C = (float*)Cp.p[z1];
        #pragma unroll
        for (int i = 0; i < FM; ++i)
            #pragma unroll
            for (int j = 0; j < FN; ++j)
                #pragma unroll
                for (int r = 0; r < 4; ++r) {
                    int m = m0 + wm*(TM/2) + i*16 + kc*4 + r;
                    int n = n0 + wn*(TN/2) + j*16 + fr;
                    i64 off = cbase + ((i64)(m >> 9) << 18) + ((i64)n << 9) + (m & 511);
                    C[off] = acc[i][j][r];
                }
    }
}

// Scaled softmax over rows of length 2048 (fp16 in place). channel path only.
__global__ __launch_bounds__(256) void softmax_rows(
    __half* __restrict__ attn, const float* __restrict__ stats,
    int rows_per_stat, float inv_count)
{
    const int ROWLEN = 2048;
    const int row = blockIdx.x;
    const int sidx = row / rows_per_stat;
    float sm = stats[2*sidx], sq = stats[2*sidx+1];
    float mean = sm * inv_count;
    float var = fmaxf(sq * inv_count - mean*mean, 0.f);
    float scale = rsqrtf(var + 1e-5f);
    __half* rp = attn + (i64)row * ROWLEN;
    const int tid = threadIdx.x;
    float v[8]; float mx = -3.4e38f;
    #pragma unroll
    for (int s = 0; s < 8; ++s) { float x = __half2float(rp[tid + s*256]) * scale; v[s] = x; mx = fmaxf(mx, x); }
    #pragma unroll
    for (int off = 32; off; off >>= 1) mx = fmaxf(mx, __shfl_xor(mx, off));
    __shared__ float red[4];
    if ((tid & 63) == 0) red[tid >> 6] = mx;
    __syncthreads();
    mx = fmaxf(fmaxf(red[0], red[1]), fmaxf(red[2], red[3]));
    float ls = 0.f;
    #pragma unroll
    for (int s = 0; s < 8; ++s) { float e = __expf(v[s] - mx); v[s] = e; ls += e; }
    #pragma unroll
    for (int off = 32; off; off >>= 1) ls += __shfl_xor(ls, off);
    __syncthreads();
    if ((tid & 63) == 0) red[tid >> 6] = ls;
    __syncthreads();
    float inv = 1.f / (red[0] + red[1] + red[2] + red[3]);
    #pragma unroll
    for (int s = 0; s < 8; ++s) rp[tid + s*256] = __float2half(v[s] * inv);
}

// 64x64 Gram partials + column sums over 256 rows. out slot = 4096 G + 64 colsum.
__global__ __launch_bounds__(256) void gram64(
    const float* __restrict__ src, float* __restrict__ parts,
    i64 bstride, i64 zs2)
{
    __shared__ float T[16][68];
    __shared__ float csred[4][64];
    const int z = blockIdx.x;
    const int tid = threadIdx.x;
    const float* base = src + (i64)(z>>3)*bstride + (i64)blockIdx.z*zs2
                      + (i64)blockIdx.y*256*512 + (z&7)*64;
    float g[4][4] = {{0.f}};
    float cs = 0.f;
    const int sr = tid >> 4, sc = (tid & 15) * 4;
    const int col = tid & 63, qq = tid >> 6;
    for (int grp = 0; grp < 16; ++grp) {
        const float4 ld = *(const float4*)&base[(i64)(grp*16 + sr)*512 + sc];
        __syncthreads();
        *(float4*)&T[sr][sc] = ld;
        __syncthreads();
        #pragma unroll
        for (int rr = 0; rr < 16; ++rr) {
            const float4 a = *(const float4*)&T[rr][sr*4];
            const float4 b = *(const float4*)&T[rr][sc];
            g[0][0]+=a.x*b.x; g[0][1]+=a.x*b.y; g[0][2]+=a.x*b.z; g[0][3]+=a.x*b.w;
            g[1][0]+=a.y*b.x; g[1][1]+=a.y*b.y; g[1][2]+=a.y*b.z; g[1][3]+=a.y*b.w;
            g[2][0]+=a.z*b.x; g[2][1]+=a.z*b.y; g[2][2]+=a.z*b.z; g[2][3]+=a.z*b.w;
            g[3][0]+=a.w*b.x; g[3][1]+=a.w*b.y; g[3][2]+=a.w*b.z; g[3][3]+=a.w*b.w;
        }
        cs += T[qq*4+0][col] + T[qq*4+1][col] + T[qq*4+2][col] + T[qq*4+3][col];
    }
    float* out = parts + (i64)((blockIdx.z*gridDim.y + blockIdx.y)*gridDim.x + blockIdx.x)*4160;
    #pragma unroll
    for (int x = 0; x < 4; ++x)
        #pragma unroll
        for (int y = 0; y < 4; ++y)
            out[(sr*4+x)*64 + sc + y] = g[x][y];
    csred[qq][col] = cs;
    __syncthreads();
    if (tid < 64) out[4096 + tid] = csred[0][tid]+csred[1][tid]+csred[2][tid]+csred[3][tid];
}

// scale/shift per (s,z): S1 = qbar.kbar, S2 = <G_Q, G_K>_F
__global__ __launch_bounds__(256) void fin_stats(
    const float* __restrict__ gq, const float* __restrict__ gk,
    float* __restrict__ ss)
{
    const int z = blockIdx.x, s = blockIdx.y;
    const int tid = threadIdx.x;
    const int lane = tid & 63, wid = tid >> 6;
    const float* q0 = gq + (i64)((s*2+0)*32 + z)*4160;
    const float* q1 = gq + (i64)((s*2+1)*32 + z)*4160;
    float p2 = 0.f;
    for (int i = tid; i < 4096; i += 256) {
        float a = q0[i] + q1[i];
        float b = 0.f;
        #pragma unroll
        for (int c = 0; c < 8; ++c) b += gk[(i64)(c*32 + z)*4160 + i];
        p2 += a*b;
    }
    float p1 = 0.f;
    if (tid < 64) {
        float a = q0[4096+tid] + q1[4096+tid];
        float b = 0.f;
        #pragma unroll
        for (int c = 0; c < 8; ++c) b += gk[(i64)(c*32 + z)*4160 + 4096 + tid];
        p1 = a*b;
    }
    #pragma unroll
    for (int off = 32; off; off >>= 1) { p2 += __shfl_xor(p2, off); p1 += __shfl_xor(p1, off); }
    __shared__ float r2[4], r1[4];
    if (lane == 0) { r2[wid] = p2; r1[wid] = p1; }
    __syncthreads();
    if (tid == 0) {
        float S2 = r2[0]+r2[1]+r2[2]+r2[3];
        float S1 = r1[0]+r1[1]+r1[2]+r1[3];
        const float inv = 1.f/1048576.f;
        float mu = S1*inv;
        float var = fmaxf(S2*inv - mu*mu, 0.f);
        float sc = rsqrtf(var + 1e-5f);
        ss[(s*32+z)*2] = sc;
        ss[(s*32+z)*2+1] = sc*mu;
    }
}

// Fused spatial attention: per (qtile, b*8+h, stream): ctx = softmax_flash(Q K^T) V
__global__ __launch_bounds__(256) void flash_spatial(
    const float* __restrict__ Qall, const float* __restrict__ Km,
    const float* __restrict__ Vm, const float* __restrict__ ss,
    float* __restrict__ ctxall)
{
    __shared__ ushort QPh[2][64][40], QPl[2][64][40];   // Q in prologue, P in loop
    __shared__ ushort Kh[2][64][40], Kl[2][64][40];
    __shared__ ushort Vh[2][64][40], Vl[2][64][40];
    __shared__ float denl[2][64];
    const int qt = blockIdx.x, zz = blockIdx.y, s = blockIdx.z;
    const int b = zz >> 3, hD = (zz & 7) * 64;
    const float scale = ss[(s*32+zz)*2], shift = ss[(s*32+zz)*2+1];
    const float* Qb = Qall + ((i64)(s*4+b)*512 + qt*64) * 512;
    const float* Kb = Km + (i64)b*2048*512;
    const float* Vb = Vm + (i64)b*2048*512;
    const int tid = threadIdx.x, lane = tid & 63, wid = tid >> 6;
    const int wq = wid >> 1, wk = wid & 1;
    const int fr = lane & 15, kc = lane >> 4;

    float4 kreg[2][2], vreg[2][2];
    auto kload = [&](int kv0){
        #pragma unroll
        for (int pl = 0; pl < 2; ++pl)
            #pragma unroll
            for (int si = 0; si < 2; ++si) {
                int v = tid + si*256, r = v >> 3, c4 = v & 7;
                kreg[pl][si] = *(const float4*)&Kb[(i64)(kv0 + r)*512 + hD + pl*32 + c4*4];
            }
    };
    auto kstore = [&](){
        #pragma unroll
        for (int pl = 0; pl < 2; ++pl)
            #pragma unroll
            for (int si = 0; si < 2; ++si) {
                int v = tid + si*256, r = v >> 3, c4 = v & 7;
                float vv[4] = {kreg[pl][si].x, kreg[pl][si].y, kreg[pl][si].z, kreg[pl][si].w};
                ushort h[4], l[4];
                #pragma unroll
                for (int t = 0; t < 4; ++t) split1(vv[t], h[t], l[t]);
                int pc = (c4 ^ sw2of(r)) * 4;
                *(ushort4*)&Kh[pl][r][pc] = make_ushort4(h[0],h[1],h[2],h[3]);
                *(ushort4*)&Kl[pl][r][pc] = make_ushort4(l[0],l[1],l[2],l[3]);
            }
    };
    auto vload = [&](int kv0){
        #pragma unroll
        for (int pl = 0; pl < 2; ++pl)
            #pragma unroll
            for (int si = 0; si < 2; ++si) {
                int v = tid + si*256, r = v & 63, k4 = v >> 6;
                float x0 = Vb[(i64)(kv0 + pl*32 + k4*4 + 0)*512 + hD + r];
                float x1 = Vb[(i64)(kv0 + pl*32 + k4*4 + 1)*512 + hD + r];
                float x2 = Vb[(i64)(kv0 + pl*32 + k4*4 + 2)*512 + hD + r];
                float x3 = Vb[(i64)(kv0 + pl*32 + k4*4 + 3)*512 + hD + r];
                vreg[pl][si] = make_float4(x0,x1,x2,x3);
            }
    };
    auto vstore = [&](){
        #pragma unroll
        for (int pl = 0; pl < 2; ++pl)
            #pragma unroll
            for (int si = 0; si < 2; ++si) {
                int v = tid + si*256, r = v & 63, k4 = v >> 6;
                float vv[4] = {vreg[pl][si].x, vreg[pl][si].y, vreg[pl][si].z, vreg[pl][si].w};
                ushort h[4], l[4];
                #pragma unroll
                for (int t = 0; t < 4; ++t) split1(vv[t], h[t], l[t]);
                int pc = (k4 ^ sw2of(r)) * 4;
                *(ushort4*)&Vh[pl][r][pc] = make_ushort4(h[0],h[1],h[2],h[3]);
                *(ushort4*)&Vl[pl][r][pc] = make_ushort4(l[0],l[1],l[2],l[3]);
            }
    };

    // prologue
    #pragma unroll
    for (int pl = 0; pl < 2; ++pl)
        stage_kc<64>(Qb, 512, 0, hD + pl*32, QPh[pl], QPl[pl], tid);
    kload(0);
    __syncthreads();                      // Q visible
    bf16x8 qh[2][2], ql[2][2];            // [i][ks] hoisted for all 32 tiles
    #pragma unroll
    for (int i = 0; i < 2; ++i)
        #pragma unroll
        for (int ks = 0; ks < 2; ++ks) {
            int row = wq*32 + i*16 + fr;
            qh[i][ks] = frag_read(QPh[ks], row, kc);
            ql[i][ks] = frag_read(QPl[ks], row, kc);
        }
    kstore();
    vload(0);
    __syncthreads();                      // K0 visible; Q reads done (P may overwrite)

    f32x4 ctx[2][2];
    #pragma unroll
    for (int i = 0; i < 2; ++i)
        #pragma unroll
        for (int j = 0; j < 2; ++j) ctx[i][j] = (f32x4){0.f,0.f,0.f,0.f};
    float den_lr[2][4] = {{0.f}};

    for (int t = 0; t < 32; ++t) {
        // S = Q K^T on this kv tile
        f32x4 sacc[2][2];
        #pragma unroll
        for (int i = 0; i < 2; ++i)
            #pragma unroll
            for (int j = 0; j < 2; ++j) sacc[i][j] = (f32x4){0.f,0.f,0.f,0.f};
        #pragma unroll
        for (int ks = 0; ks < 2; ++ks) {
            bf16x8 khf[2], klf[2];
            #pragma unroll
            for (int j = 0; j < 2; ++j) {
                int row = wk*32 + j*16 + fr;
                khf[j] = frag_read(Kh[ks], row, kc);
                klf[j] = frag_read(Kl[ks], row, kc);
            }
            #pragma unroll
            for (int i = 0; i < 2; ++i)
                #pragma unroll
                for (int j = 0; j < 2; ++j) {
                    sacc[i][j] = MFMA_BF16(qh[i][ks], khf[j], sacc[i][j], 0, 0, 0);
                    sacc[i][j] = MFMA_BF16(qh[i][ks], klf[j], sacc[i][j], 0, 0, 0);
                    sacc[i][j] = MFMA_BF16(ql[i][ks], khf[j], sacc[i][j], 0, 0, 0);
                }
        }
        if (t + 1 < 32) kload((t+1)*64);
        // P = exp(scale*s - shift), den accumulate, split to bf16 pair
        ushort ph[2][2][4], plo[2][2][4];
        #pragma unroll
        for (int i = 0; i < 2; ++i)
            #pragma unroll
            for (int j = 0; j < 2; ++j)
                #pragma unroll
                for (int r = 0; r < 4; ++r) {
                    float p = __expf(sacc[i][j][r]*scale - shift);
                    den_lr[i][r] += p;
                    split1(p, ph[i][j][r], plo[i][j][r]);
                }
        __syncthreads();                  // K reads done; prev P/V reads done
        vstore();
        #pragma unroll
        for (int i = 0; i < 2; ++i)
            #pragma unroll
            for (int j = 0; j < 2; ++j)
                #pragma unroll
                for (int r = 0; r < 4; ++r) {
                    int row = wq*32 + i*16 + kc*4 + r;
                    int c = j*16 + fr;
                    int pc2 = (((c >> 2) ^ sw2of(row)) << 2) | (c & 3);
                    QPh[wk][row][pc2] = ph[i][j][r];
                    QPl[wk][row][pc2] = plo[i][j][r];
                }
        if (t + 1 < 32) kstore();
        __syncthreads();                  // P, V, K(t+1) visible
        // ctx += P V
        #pragma unroll
        for (int ks = 0; ks < 2; ++ks) {
            bf16x8 vhf[2], vlf[2], pah[2], pal[2];
            #pragma unroll
            for (int j = 0; j < 2; ++j) {
                int row = wk*32 + j*16 + fr;
                vhf[j] = frag_read(Vh[ks], row, kc);
                vlf[j] = frag_read(Vl[ks], row, kc);
            }
            #pragma unroll
            for (int i = 0; i < 2; ++i) {
                int prow = wq*32 + i*16 + fr;
                pah[i] = frag_read(QPh[ks], prow, kc);
                pal[i] = frag_read(QPl[ks], prow, kc);
            }
            #pragma unroll
            for (int i = 0; i < 2; ++i)
                #pragma unroll
                for (int j = 0; j < 2; ++j) {
                    ctx[i][j] = MFMA_BF16(pah[i], vhf[j], ctx[i][j], 0, 0, 0);
                    ctx[i][j] = MFMA_BF16(pah[i], vlf[j], ctx[i][j], 0, 0, 0);
                    ctx[i][j] = MFMA_BF16(pal[i], vhf[j], ctx[i][j], 0, 0, 0);
                }
        }
        if (t + 1 < 32) vload((t+1)*64);
    }

    // reduce den over fr lanes, combine wk halves, write ctx/den
    #pragma unroll
    for (int i = 0; i < 2; ++i)
        #pragma unroll
        for (int r = 0; r < 4; ++r) {
            float d = den_lr[i][r];
            d += __shfl_xor(d, 1); d += __shfl_xor(d, 2);
            d += __shfl_xor(d, 4); d += __shfl_xor(d, 8);
            if (fr == 0) denl[wk][wq*32 + i*16 + kc*4 + r] = d;
        }
    __syncthreads();
    #pragma unroll
    for (int i = 0; i < 2; ++i)
        #pragma unroll
        for (int j = 0; j < 2; ++j)
            #pragma unroll
            for (int r = 0; r < 4; ++r) {
                int row = wq*32 + i*16 + kc*4 + r;
                int col = wk*32 + j*16 + fr;
                float dv = denl[0][row] + denl[1][row];
                ctxall[((i64)(s*4+b)*512 + qt*64 + row)*512 + hD + col] = ctx[i][j][r] / dv;
            }
}

static inline P4 p4x(const void* a, const void* b, const void* c, const void* d){
    P4 x; x.p[0]=a; x.p[1]=b; x.p[2]=c; x.p[3]=d; return x;
}
static inline P4 p4x(const void* a){ return p4x(a,a,a,a); }

extern "C" void kernel_launch(void* const* d_in, const int* in_sizes, int n_in,
                              void* d_out, int out_size, void* d_ws, size_t ws_size,
                              hipStream_t stream)
{
    (void)in_sizes; (void)n_in; (void)out_size;
    const int Bb = 4, Ntok = 512, E = 512, Cc = 2048, M4 = 2048;
    const float* emb[4] = {(const float*)d_in[0], (const float*)d_in[1],
                           (const float*)d_in[2], (const float*)d_in[3]};
    const float* embC = (const float*)d_in[4];
    const float* Wq[4] = {(const float*)d_in[5], (const float*)d_in[6],
                          (const float*)d_in[7], (const float*)d_in[8]};
    const float* Wk  = (const float*)d_in[9];
    const float* Wv  = (const float*)d_in[10];
    const float* WqC = (const float*)d_in[11];
    const float* WkC = (const float*)d_in[12];
    const float* WvC = (const float*)d_in[13];
    const float* Wo[4] = {(const float*)d_in[14], (const float*)d_in[15],
                          (const float*)d_in[16], (const float*)d_in[17]};
    float* out = (float*)d_out;

    char* ws = (char*)d_ws;
    const size_t MB = 1024*1024;
    if (ws_size < 128*MB + 512) return;
    float*  QC    = (float*)(ws + 0);
    float*  KC    = (float*)(ws + 16*MB);
    float*  VC    = (float*)(ws + 32*MB);
    __half* attnC = (__half*)(ws + 48*MB);   // 32MB
    float*  KVS   = (float*)(ws + 80*MB);
    float*  Km    = (float*)(ws + 96*MB);
    float*  Vm    = (float*)(ws + 112*MB);
    // regions reused after the channel stage:
    float*  Qall  = (float*)(ws + 0);        // 16MB (QC dead)
    float*  ctx   = (float*)(ws + 16*MB);    // 16MB (KC dead)
    float*  GQp   = (float*)(ws + 32*MB);    // 4.3MB (VC dead)
    float*  GKp   = (float*)(ws + 37*MB);    // 4.3MB
    float*  ssbuf = (float*)(ws + 42*MB);    // 1KB
    float*  stats = (float*)(ws + 128*MB);   // channel stats

    hipMemsetAsync(stats, 0, 512, stream);

    // ---- channel projections QC/KC/VC = embC @ W^T (batched over {q,k,v} x b) ----
    gemm_mfma<128,128,float,0><<<dim3(Cc/128, Ntok/128, 12), 256, 0, stream>>>(
        p4x(embC), p4x(WqC, WkC, WvC, WvC), p4x(QC, KC, VC, VC), nullptr,
        Cc, 4,
        (i64)Ntok*Cc, Cc, 1,   0, Cc, 1,   (i64)Ntok*Cc, Cc, 1);
    // ---- attn_c[c,d] = sum_n QC[n,c] KC[n,d] + stats ----
    gemm_mfma<128,128,float,1><<<dim3(Cc/128, Cc/128, Bb), 256, 0, stream>>>(
        p4x(QC), p4x(KC), p4x(attnC), stats,
        Ntok, 4,
        (i64)Ntok*Cc, 1, Cc,   (i64)Ntok*Cc, 1, Cc,   (i64)Cc*Cc, Cc, 1);
    softmax_rows<<<dim3(Bb*Cc), 256, 0, stream>>>(attnC, stats, Cc, 1.f/((float)Cc*(float)Cc));
    // ---- ctx_c = sim @ VC^T, scatter into KV_S ----
    gemm_mfma<128,128,__half,2><<<dim3(Ntok/128, Cc/128, Bb), 256, 0, stream>>>(
        p4x(attnC), p4x(VC), p4x(KVS), nullptr,
        Cc, 4,
        (i64)Cc*Cc, Cc, 1,   (i64)Ntok*Cc, Cc, 1,   (i64)M4*E, 0, 0);
    // ---- K, V = KV_S @ W^T (batched over {k,v} x b) ----
    gemm_mfma<128,128,float,0><<<dim3(E/128, M4/128, 8), 256, 0, stream>>>(
        p4x(KVS), p4x(Wk, Wv, Wv, Wv), p4x(Km, Vm, Vm, Vm), nullptr,
        E, 4,
        (i64)M4*E, E, 1,   0, E, 1,   (i64)M4*E, E, 1);
    // ---- Q projections, all 4 streams batched ----
    gemm_mfma<128,128,float,0><<<dim3(E/128, Ntok/128, 16), 256, 0, stream>>>(
        p4x(emb[0], emb[1], emb[2], emb[3]),
        p4x(Wq[0], Wq[1], Wq[2], Wq[3]),
        p4x(Qall, Qall + 1048576, Qall + 2097152, Qall + 3145728), nullptr,
        E, 4,
        (i64)Ntok*E, E, 1,   0, E, 1,   (i64)Ntok*E, E, 1);
    // ---- Gram stats: G_K (once), G_Q (4 streams), finalize ----
    gram64<<<dim3(32, 8, 1), 256, 0, stream>>>(Km, GKp, (i64)M4*E, 0);
    gram64<<<dim3(32, 2, 4), 256, 0, stream>>>(Qall, GQp, (i64)Ntok*E, (i64)4*Ntok*E);
    fin_stats<<<dim3(32, 4), 256, 0, stream>>>(GQp, GKp, ssbuf);
    // ---- fused spatial attention ----
    flash_spatial<<<dim3(8, 32, 4), 256, 0, stream>>>(Qall, Km, Vm, ssbuf, ctx);
    // ---- output projections, all 4 streams batched ----
    gemm_mfma<128,128,float,0><<<dim3(E/128, Ntok/128, 16), 256, 0, stream>>>(
        p4x(ctx, ctx + 1048576, ctx + 2097152, ctx + 3145728),
        p4x(Wo[0], Wo[1], Wo[2], Wo[3]),
        p4x(out, out + 1048576, out + 2097152, out + 3145728), nullptr,
        E, 4,
        (i64)Ntok*E, E, 1,   0, E, 1,   (i64)Ntok*E, E, 1);
}

// Round 4
// 739.359 us; speedup vs baseline: 5.3455x; 1.1537x over previous
//
#include <hip/hip_runtime.h>
#include <hip/hip_bf16.h>
#include <hip/hip_fp16.h>

typedef long long i64;
typedef unsigned int u32;
typedef __attribute__((ext_vector_type(8))) short bf16x8;
typedef __attribute__((ext_vector_type(4))) float f32x4;

#define MFMA_BF16 __builtin_amdgcn_mfma_f32_16x16x32_bf16

__device__ __forceinline__ void glds16(const void* g, void* l){
    __builtin_amdgcn_global_load_lds((const __attribute__((address_space(1))) u32*)g,
                                     (__attribute__((address_space(3))) u32*)l, 16, 0, 0);
}
// fp32 -> bf16 hi (truncate) + bf16 lo (residual). a ~= hi + lo, |err| ~ 2^-16 |a|
__device__ __forceinline__ void split1(float x, ushort& h, ushort& l){
    unsigned b = __float_as_uint(x);
    h = (ushort)(b >> 16);
    float hf = __uint_as_float(b & 0xFFFF0000u);
    float lf = x - hf;
    l = (ushort)(__float_as_uint(lf) >> 16);
}
__device__ __forceinline__ float bfpair(ushort h, ushort l){
    return __uint_as_float((u32)h << 16) + __uint_as_float((u32)l << 16);
}
__device__ __forceinline__ void ld4h(const __half* p, float v[4]){
    const __half2* q = (const __half2*)p;
    __half2 a = q[0], b = q[1];
    v[0]=__low2float(a); v[1]=__high2float(a);
    v[2]=__low2float(b); v[3]=__high2float(b);
}
// swizzled [64][64] bf16 tile read: 16B-group g (0..7) XORed by row&7
__device__ __forceinline__ bf16x8 fragS(const ushort* P, int row, int g){
    return *(const bf16x8*)&P[row*64 + (((g) ^ (row & 7)) << 3)];
}

struct P4 { const void* p[4]; };
struct I4 { int v[4]; };

// ---------------- pre-split: fp32 -> bf16 hi/lo planes ----------------
struct PSJobs { const float* s[13]; ushort* d[13]; int st[14]; };
__global__ __launch_bounds__(256) void presplit(PSJobs J){
    int bid = blockIdx.x, j = 0;
    while (bid >= J.st[j+1]) ++j;
    i64 base = (i64)(bid - J.st[j])*2048 + threadIdx.x*8;
    i64 loOff = (i64)(J.st[j+1] - J.st[j])*2048;
    const float* sp = J.s[j]; ushort* dp = J.d[j];
    float4 a = *(const float4*)&sp[base];
    float4 b = *(const float4*)&sp[base+4];
    float v[8] = {a.x,a.y,a.z,a.w,b.x,b.y,b.z,b.w};
    ushort h[8], l[8];
    #pragma unroll
    for (int t = 0; t < 8; ++t) split1(v[t], h[t], l[t]);
    *(ushort4*)&dp[base]         = make_ushort4(h[0],h[1],h[2],h[3]);
    *(ushort4*)&dp[base+4]       = make_ushort4(h[4],h[5],h[6],h[7]);
    *(ushort4*)&dp[loOff+base]   = make_ushort4(l[0],l[1],l[2],l[3]);
    *(ushort4*)&dp[loOff+base+4] = make_ushort4(l[4],l[5],l[6],l[7]);
}

// ---------------- GEMM on pre-split planes, bf16x3, global_load_lds staging ----------------
// C[m,n] = sum_k A[m,k]*B[n,k]; A/B k-contiguous bf16 hi planes (lo at +aLo/+bLo).
// AF16: A is fp16 (reg-stage, exact split). OUT: 0 fp32; 1 bf16 planes, per-z1
// cfg = cmode.v[z1] = (transpose<<30)|cld; 2 fp16 + per-z stats; 3 KVS-scatter planes.
template<bool AF16, int OUT>
__global__ __launch_bounds__(256) void gemm_ps(
    P4 Ap, P4 Bp, P4 Cp, I4 cmode, float* __restrict__ stats,
    int K, int zdiv,
    i64 ab2, i64 alda, i64 aLo,
    i64 bb2, i64 bldb, i64 bLo,
    i64 cb2, i64 cld, i64 cLo)
{
    __shared__ ushort Ah[4096], Al[4096], Bh[4096], Bl[4096]; // [128][32] linear
    __shared__ float sred[4], qred[4];
    const int z = blockIdx.z, z1 = z / zdiv, z2 = z % zdiv;
    const int m0 = blockIdx.y*128, n0 = blockIdx.x*128;
    const int tid = threadIdx.x, lane = tid & 63, wid = tid >> 6;
    const int wm = wid >> 1, wn = wid & 1, fr = lane & 15, kc = lane >> 4;
    const ushort* Aps = (const ushort*)Ap.p[z1] + (i64)z2*ab2 + (i64)m0*alda;
    const __half* Af  = (const __half*)Ap.p[z1] + (i64)z2*ab2 + (i64)m0*alda;
    const ushort* Bps = (const ushort*)Bp.p[z1] + (i64)z2*bb2 + (i64)n0*bldb;

    f32x4 acc[4][4];
    #pragma unroll
    for (int i = 0; i < 4; ++i)
        #pragma unroll
        for (int j = 0; j < 4; ++j) acc[i][j] = (f32x4){0.f,0.f,0.f,0.f};

    for (int k0 = 0; k0 < K; k0 += 32) {
        if (!AF16) {
            #pragma unroll
            for (int q = 0; q < 2; ++q) {
                int r = wid*32 + q*16 + (lane>>2);
                const ushort* sp = Aps + (i64)r*alda + k0 + (lane&3)*8;
                glds16(sp,       &Ah[(wid*32+q*16)*32]);
                glds16(sp + aLo, &Al[(wid*32+q*16)*32]);
            }
        } else {
            #pragma unroll
            for (int s4 = 0; s4 < 4; ++s4) {
                int v = tid + s4*256; int r = v >> 3, c4 = v & 7;
                float vals[4]; ld4h(&Af[(i64)r*alda + k0 + c4*4], vals);
                ushort h[4], l[4];
                #pragma unroll
                for (int t = 0; t < 4; ++t) split1(vals[t], h[t], l[t]);
                *(ushort4*)&Ah[r*32 + c4*4] = make_ushort4(h[0],h[1],h[2],h[3]);
                *(ushort4*)&Al[r*32 + c4*4] = make_ushort4(l[0],l[1],l[2],l[3]);
            }
        }
        #pragma unroll
        for (int q = 0; q < 2; ++q) {
            int r = wid*32 + q*16 + (lane>>2);
            const ushort* sp = Bps + (i64)r*bldb + k0 + (lane&3)*8;
            glds16(sp,       &Bh[(wid*32+q*16)*32]);
            glds16(sp + bLo, &Bl[(wid*32+q*16)*32]);
        }
        __syncthreads();
        bf16x8 a_h[4], a_l[4], b_h[4], b_l[4];
        #pragma unroll
        for (int i = 0; i < 4; ++i) {
            int row = wm*64 + i*16 + fr;
            a_h[i] = *(const bf16x8*)&Ah[row*32 + kc*8];
            a_l[i] = *(const bf16x8*)&Al[row*32 + kc*8];
        }
        #pragma unroll
        for (int j = 0; j < 4; ++j) {
            int row = wn*64 + j*16 + fr;
            b_h[j] = *(const bf16x8*)&Bh[row*32 + kc*8];
            b_l[j] = *(const bf16x8*)&Bl[row*32 + kc*8];
        }
        #pragma unroll
        for (int i = 0; i < 4; ++i)
            #pragma unroll
            for (int j = 0; j < 4; ++j) {
                acc[i][j] = MFMA_BF16(a_h[i], b_h[j], acc[i][j], 0, 0, 0);
                acc[i][j] = MFMA_BF16(a_h[i], b_l[j], acc[i][j], 0, 0, 0);
                acc[i][j] = MFMA_BF16(a_l[i], b_h[j], acc[i][j], 0, 0, 0);
            }
        __syncthreads();
    }

    const i64 cbase = (i64)z2*cb2;
    if (OUT == 0) {
        float* C = (float*)Cp.p[z1];
        #pragma unroll
        for (int i = 0; i < 4; ++i)
            #pragma unroll
            for (int j = 0; j < 4; ++j)
                #pragma unroll
                for (int r = 0; r < 4; ++r) {
                    int m = m0 + wm*64 + i*16 + kc*4 + r;
                    int n = n0 + wn*64 + j*16 + fr;
                    C[cbase + (i64)m*cld + n] = acc[i][j][r];
                }
    } else if (OUT == 1) {
        ushort* C = (ushort*)Cp.p[z1];
        const int cfg = cmode.v[z1];
        const int tr = cfg >> 30;
        const i64 ldv = cfg & 0x3FFFFFFF;
        #pragma unroll
        for (int i = 0; i < 4; ++i)
            #pragma unroll
            for (int j = 0; j < 4; ++j)
                #pragma unroll
                for (int r = 0; r < 4; ++r) {
                    int m = m0 + wm*64 + i*16 + kc*4 + r;
                    int n = n0 + wn*64 + j*16 + fr;
                    ushort h, l; split1(acc[i][j][r], h, l);
                    i64 off = cbase + (tr ? (i64)n*ldv + m : (i64)m*ldv + n);
                    C[off] = h; C[off + cLo] = l;
                }
    } else if (OUT == 2) {
        __half* C = (__half*)Cp.p[z1];
        float ls = 0.f, lq = 0.f;
        #pragma unroll
        for (int i = 0; i < 4; ++i)
            #pragma unroll
            for (int j = 0; j < 4; ++j)
                #pragma unroll
                for (int r = 0; r < 4; ++r) {
                    int m = m0 + wm*64 + i*16 + kc*4 + r;
                    int n = n0 + wn*64 + j*16 + fr;
                    float v = acc[i][j][r];
                    ls += v; lq += v*v;
                    C[cbase + (i64)m*cld + n] = __float2half(v);
                }
        #pragma unroll
        for (int off = 32; off; off >>= 1) { ls += __shfl_xor(ls, off); lq += __shfl_xor(lq, off); }
        if (lane == 0) { sred[wid] = ls; qred[wid] = lq; }
        __syncthreads();
        if (tid == 0) {
            atomicAdd(&stats[2*z],   sred[0]+sred[1]+sred[2]+sred[3]);
            atomicAdd(&stats[2*z+1], qred[0]+qred[1]+qred[2]+qred[3]);
        }
    } else {
        ushort* C = (ushort*)Cp.p[z1];
        #pragma unroll
        for (int i = 0; i < 4; ++i)
            #pragma unroll
            for (int j = 0; j < 4; ++j)
                #pragma unroll
                for (int r = 0; r < 4; ++r) {
                    int m = m0 + wm*64 + i*16 + kc*4 + r;
                    int n = n0 + wn*64 + j*16 + fr;
                    ushort h, l; split1(acc[i][j][r], h, l);
                    i64 off = cbase + ((i64)(m >> 9) << 18) + ((i64)n << 9) + (m & 511);
                    C[off] = h; C[off + cLo] = l;
                }
    }
}

// ---------------- channel softmax (fp16 in place) ----------------
__global__ __launch_bounds__(256) void softmax_rows(
    __half* __restrict__ attn, const float* __restrict__ stats,
    int rows_per_stat, float inv_count)
{
    const int ROWLEN = 2048;
    const int row = blockIdx.x;
    const int sidx = row / rows_per_stat;
    float sm = stats[2*sidx], sq = stats[2*sidx+1];
    float mean = sm * inv_count;
    float var = fmaxf(sq * inv_count - mean*mean, 0.f);
    float scale = rsqrtf(var + 1e-5f);
    __half* rp = attn + (i64)row * ROWLEN;
    const int tid = threadIdx.x;
    float v[8]; float mx = -3.4e38f;
    #pragma unroll
    for (int s = 0; s < 8; ++s) { float x = __half2float(rp[tid + s*256]) * scale; v[s] = x; mx = fmaxf(mx, x); }
    #pragma unroll
    for (int off = 32; off; off >>= 1) mx = fmaxf(mx, __shfl_xor(mx, off));
    __shared__ float red[4];
    if ((tid & 63) == 0) red[tid >> 6] = mx;
    __syncthreads();
    mx = fmaxf(fmaxf(red[0], red[1]), fmaxf(red[2], red[3]));
    float ls = 0.f;
    #pragma unroll
    for (int s = 0; s < 8; ++s) { float e = __expf(v[s] - mx); v[s] = e; ls += e; }
    #pragma unroll
    for (int off = 32; off; off >>= 1) ls += __shfl_xor(ls, off);
    __syncthreads();
    if ((tid & 63) == 0) red[tid >> 6] = ls;
    __syncthreads();
    float inv = 1.f / (red[0] + red[1] + red[2] + red[3]);
    #pragma unroll
    for (int s = 0; s < 8; ++s) rp[tid + s*256] = __float2half(v[s] * inv);
}

// ---------------- 64x64 Gram partials + column sums over 256 rows (planes input) ----------------
__global__ __launch_bounds__(256) void gram64(
    const ushort* __restrict__ hi, i64 loOff, float* __restrict__ parts,
    i64 bstride, i64 zs2)
{
    __shared__ float T[16][68];
    __shared__ float csred[4][64];
    const int z = blockIdx.x;
    const int tid = threadIdx.x;
    const ushort* base = hi + (i64)(z>>3)*bstride + (i64)blockIdx.z*zs2
                       + (i64)blockIdx.y*256*512 + (z&7)*64;
    float g[4][4] = {{0.f}};
    float cs = 0.f;
    const int sr = tid >> 4, sc = (tid & 15) * 4;
    const int col = tid & 63, qq = tid >> 6;
    for (int grp = 0; grp < 16; ++grp) {
        i64 idx = (i64)(grp*16 + sr)*512 + sc;
        ushort4 hv = *(const ushort4*)&base[idx];
        ushort4 lv = *(const ushort4*)&base[loOff + idx];
        float4 ld;
        ld.x = bfpair(hv.x, lv.x); ld.y = bfpair(hv.y, lv.y);
        ld.z = bfpair(hv.z, lv.z); ld.w = bfpair(hv.w, lv.w);
        __syncthreads();
        *(float4*)&T[sr][sc] = ld;
        __syncthreads();
        #pragma unroll
        for (int rr = 0; rr < 16; ++rr) {
            const float4 a = *(const float4*)&T[rr][sr*4];
            const float4 b = *(const float4*)&T[rr][sc];
            g[0][0]+=a.x*b.x; g[0][1]+=a.x*b.y; g[0][2]+=a.x*b.z; g[0][3]+=a.x*b.w;
            g[1][0]+=a.y*b.x; g[1][1]+=a.y*b.y; g[1][2]+=a.y*b.z; g[1][3]+=a.y*b.w;
            g[2][0]+=a.z*b.x; g[2][1]+=a.z*b.y; g[2][2]+=a.z*b.z; g[2][3]+=a.z*b.w;
            g[3][0]+=a.w*b.x; g[3][1]+=a.w*b.y; g[3][2]+=a.w*b.z; g[3][3]+=a.w*b.w;
        }
        cs += T[qq*4+0][col] + T[qq*4+1][col] + T[qq*4+2][col] + T[qq*4+3][col];
    }
    float* outp = parts + (i64)((blockIdx.z*gridDim.y + blockIdx.y)*gridDim.x + blockIdx.x)*4160;
    #pragma unroll
    for (int x = 0; x < 4; ++x)
        #pragma unroll
        for (int y = 0; y < 4; ++y)
            outp[(sr*4+x)*64 + sc + y] = g[x][y];
    csred[qq][col] = cs;
    __syncthreads();
    if (tid < 64) outp[4096 + tid] = csred[0][tid]+csred[1][tid]+csred[2][tid]+csred[3][tid];
}

// scale/shift per (s,z): S1 = qbar.kbar, S2 = <G_Q, G_K>_F
__global__ __launch_bounds__(256) void fin_stats(
    const float* __restrict__ gq, const float* __restrict__ gk,
    float* __restrict__ ss)
{
    const int z = blockIdx.x, s = blockIdx.y;
    const int tid = threadIdx.x;
    const int lane = tid & 63, wid = tid >> 6;
    const float* q0 = gq + (i64)((s*2+0)*32 + z)*4160;
    const float* q1 = gq + (i64)((s*2+1)*32 + z)*4160;
    float p2 = 0.f;
    for (int i = tid; i < 4096; i += 256) {
        float a = q0[i] + q1[i];
        float b = 0.f;
        #pragma unroll
        for (int c = 0; c < 8; ++c) b += gk[(i64)(c*32 + z)*4160 + i];
        p2 += a*b;
    }
    float p1 = 0.f;
    if (tid < 64) {
        float a = q0[4096+tid] + q1[4096+tid];
        float b = 0.f;
        #pragma unroll
        for (int c = 0; c < 8; ++c) b += gk[(i64)(c*32 + z)*4160 + 4096 + tid];
        p1 = a*b;
    }
    #pragma unroll
    for (int off = 32; off; off >>= 1) { p2 += __shfl_xor(p2, off); p1 += __shfl_xor(p1, off); }
    __shared__ float r2[4], r1[4];
    if (lane == 0) { r2[wid] = p2; r1[wid] = p1; }
    __syncthreads();
    if (tid == 0) {
        float S2 = r2[0]+r2[1]+r2[2]+r2[3];
        float S1 = r1[0]+r1[1]+r1[2]+r1[3];
        const float inv = 1.f/1048576.f;
        float mu = S1*inv;
        float var = fmaxf(S2*inv - mu*mu, 0.f);
        float sc = rsqrtf(var + 1e-5f);
        ss[(s*32+z)*2] = sc;
        ss[(s*32+z)*2+1] = sc*mu;
    }
}

// ---------------- fused spatial flash attention on planes ----------------
__global__ __launch_bounds__(256) void flash_ps(
    const ushort* __restrict__ Qp, const ushort* __restrict__ Kp,
    const ushort* __restrict__ Vtp, const float* __restrict__ ss,
    ushort* __restrict__ ctxp)
{
    __shared__ ushort QPh[4096], QPl[4096];        // Q in prologue, P in loop
    __shared__ ushort Kh[4096], Kl[4096];
    __shared__ ushort Vh[2][4096], Vl[2][4096];
    __shared__ float denl[2][64];
    const int qt = blockIdx.x, zz = blockIdx.y, s = blockIdx.z;
    const int b = zz >> 3, hD = (zz & 7) * 64;
    const float scale = ss[(s*32+zz)*2], shift = ss[(s*32+zz)*2+1];
    const ushort* Qb = Qp + (i64)s*2097152 + (i64)b*262144 + (i64)(qt*64)*512 + hD;
    const ushort* Kb = Kp + (i64)b*1048576 + hD;
    const ushort* Vb = Vtp + (i64)b*1048576 + (i64)hD*2048;
    const int tid = threadIdx.x, lane = tid & 63, wid = tid >> 6;
    const int wq = wid >> 1, wk = wid & 1, fr = lane & 15, kc = lane >> 4;

    auto stage64 = [&](const ushort* src, i64 ld, i64 lo, ushort* Lh, ushort* Ll){
        #pragma unroll
        for (int q = 0; q < 2; ++q) {
            int rb = wid*16 + q*8;
            int r = rb + (lane >> 3);
            int gs = (lane & 7) ^ (r & 7);
            const ushort* p = src + (i64)r*ld + gs*8;
            glds16(p,      &Lh[rb*64]);
            glds16(p + lo, &Ll[rb*64]);
        }
    };

    stage64(Qb, 512, 1048576, QPh, QPl);
    stage64(Kb, 512, 4194304, Kh, Kl);
    stage64(Vb, 2048, 4194304, Vh[0], Vl[0]);
    __syncthreads();                       // Q, K0, V0 resident

    bf16x8 qh[2][2], ql[2][2];
    #pragma unroll
    for (int i = 0; i < 2; ++i)
        #pragma unroll
        for (int ks = 0; ks < 2; ++ks) {
            int row = wq*32 + i*16 + fr;
            qh[i][ks] = fragS(QPh, row, ks*4 + kc);
            ql[i][ks] = fragS(QPl, row, ks*4 + kc);
        }
    __syncthreads();                       // all Q hoists done before P overwrites

    f32x4 ctx[2][2];
    #pragma unroll
    for (int i = 0; i < 2; ++i)
        #pragma unroll
        for (int j = 0; j < 2; ++j) ctx[i][j] = (f32x4){0.f,0.f,0.f,0.f};
    float den_lr[2][4] = {{0.f}};

    for (int t = 0; t < 32; ++t) {
        f32x4 sacc[2][2];
        #pragma unroll
        for (int i = 0; i < 2; ++i)
            #pragma unroll
            for (int j = 0; j < 2; ++j) sacc[i][j] = (f32x4){0.f,0.f,0.f,0.f};
        #pragma unroll
        for (int ks = 0; ks < 2; ++ks) {
            bf16x8 khf[2], klf[2];
            #pragma unroll
            for (int j = 0; j < 2; ++j) {
                int row = wk*32 + j*16 + fr;
                khf[j] = fragS(Kh, row, ks*4 + kc);
                klf[j] = fragS(Kl, row, ks*4 + kc);
            }
            #pragma unroll
            for (int i = 0; i < 2; ++i)
                #pragma unroll
                for (int j = 0; j < 2; ++j) {
                    sacc[i][j] = MFMA_BF16(qh[i][ks], khf[j], sacc[i][j], 0, 0, 0);
                    sacc[i][j] = MFMA_BF16(qh[i][ks], klf[j], sacc[i][j], 0, 0, 0);
                    sacc[i][j] = MFMA_BF16(ql[i][ks], khf[j], sacc[i][j], 0, 0, 0);
                }
        }
        // P = exp(scale*s - shift); den accumulate; swizzled store to QP region
        #pragma unroll
        for (int i = 0; i < 2; ++i)
            #pragma unroll
            for (int j = 0; j < 2; ++j)
                #pragma unroll
                for (int r = 0; r < 4; ++r) {
                    float p = __expf(sacc[i][j][r]*scale - shift);
                    den_lr[i][r] += p;
                    ushort h, l; split1(p, h, l);
                    int row = wq*32 + i*16 + kc*4 + r;
                    int col = wk*32 + j*16 + fr;
                    int pos = row*64 + ((((col>>3) ^ (row&7)) << 3) | (col & 7));
                    QPh[pos] = h; QPl[pos] = l;
                }
        __syncthreads();                   // P visible; all K(t) reads done
        if (t + 1 < 32) {                  // prefetch lands before next barrier drain
            stage64(Kb + (i64)((t+1)*64)*512, 512, 4194304, Kh, Kl);
            stage64(Vb + (t+1)*64, 2048, 4194304, Vh[(t+1)&1], Vl[(t+1)&1]);
        }
        #pragma unroll
        for (int ks = 0; ks < 2; ++ks) {
            bf16x8 vhf[2], vlf[2], pah[2], pal[2];
            #pragma unroll
            for (int j = 0; j < 2; ++j) {
                int row = wk*32 + j*16 + fr;
                vhf[j] = fragS(Vh[t&1], row, ks*4 + kc);
                vlf[j] = fragS(Vl[t&1], row, ks*4 + kc);
            }
            #pragma unroll
            for (int i = 0; i < 2; ++i) {
                int row = wq*32 + i*16 + fr;
                pah[i] = fragS(QPh, row, ks*4 + kc);
                pal[i] = fragS(QPl, row, ks*4 + kc);
            }
            #pragma unroll
            for (int i = 0; i < 2; ++i)
                #pragma unroll
                for (int j = 0; j < 2; ++j) {
                    ctx[i][j] = MFMA_BF16(pah[i], vhf[j], ctx[i][j], 0, 0, 0);
                    ctx[i][j] = MFMA_BF16(pah[i], vlf[j], ctx[i][j], 0, 0, 0);
                    ctx[i][j] = MFMA_BF16(pal[i], vhf[j], ctx[i][j], 0, 0, 0);
                }
        }
        __syncthreads();                   // PV reads done; drain makes K/V(t+1) resident
    }

    #pragma unroll
    for (int i = 0; i < 2; ++i)
        #pragma unroll
        for (int r = 0; r < 4; ++r) {
            float d = den_lr[i][r];
            d += __shfl_xor(d, 1); d += __shfl_xor(d, 2);
            d += __shfl_xor(d, 4); d += __shfl_xor(d, 8);
            if (fr == 0) denl[wk][wq*32 + i*16 + kc*4 + r] = d;
        }
    __syncthreads();
    ushort* Cb = ctxp + (i64)s*2097152 + (i64)b*262144;
    #pragma unroll
    for (int i = 0; i < 2; ++i)
        #pragma unroll
        for (int j = 0; j < 2; ++j)
            #pragma unroll
            for (int r = 0; r < 4; ++r) {
                int row = wq*32 + i*16 + kc*4 + r;
                int col = wk*32 + j*16 + fr;
                float dv = denl[0][row] + denl[1][row];
                ushort h, l; split1(ctx[i][j][r] / dv, h, l);
                i64 off = (i64)(qt*64 + row)*512 + hD + col;
                Cb[off] = h; Cb[off + 1048576] = l;
            }
}

static inline P4 p4x(const void* a, const void* b, const void* c, const void* d){
    P4 x; x.p[0]=a; x.p[1]=b; x.p[2]=c; x.p[3]=d; return x;
}
static inline P4 p4x(const void* a){ return p4x(a,a,a,a); }
static inline I4 i4x(int a, int b, int c, int d){ I4 x; x.v[0]=a; x.v[1]=b; x.v[2]=c; x.v[3]=d; return x; }
#define TRC(ld) ((1<<30)|(ld))   // transposed plane store with leading dim ld

extern "C" void kernel_launch(void* const* d_in, const int* in_sizes, int n_in,
                              void* d_out, int out_size, void* d_ws, size_t ws_size,
                              hipStream_t stream)
{
    (void)in_sizes; (void)n_in; (void)out_size;
    const float* emb[4] = {(const float*)d_in[0], (const float*)d_in[1],
                           (const float*)d_in[2], (const float*)d_in[3]};
    const float* embC = (const float*)d_in[4];
    const float* Wq[4] = {(const float*)d_in[5], (const float*)d_in[6],
                          (const float*)d_in[7], (const float*)d_in[8]};
    const float* Wk  = (const float*)d_in[9];
    const float* Wv  = (const float*)d_in[10];
    const float* WqC = (const float*)d_in[11];
    const float* WkC = (const float*)d_in[12];
    const float* WvC = (const float*)d_in[13];
    const float* Wo[4] = {(const float*)d_in[14], (const float*)d_in[15],
                          (const float*)d_in[16], (const float*)d_in[17]};
    float* out = (float*)d_out;

    char* ws = (char*)d_ws;
    const size_t MB = 1024*1024;
    if (ws_size < 128*MB + 512) return;
    auto U = [&](size_t mb){ return (ushort*)(ws + mb*MB); };
    // layout (MB): 0..16 embC planes -> emb planes | 16..48 WqC/WkC planes -> scores -> ctx planes
    // 48..64 WvC planes -> KVS planes -> gram parts | 64..74 small W planes
    // 74..90 QCT -> K planes | 90..106 KCT -> VT planes | 106..122 VC -> Q planes | 122..128 stats
    float* stats = (float*)(ws + 122*MB);
    float* ssbuf = (float*)(ws + 122*MB + 1024);
    float* GKp   = (float*)(ws + 48*MB);
    float* GQp   = (float*)(ws + 53*MB);
    __half* scores = (__half*)(ws + 16*MB);

    hipMemsetAsync(stats, 0, 512, stream);

    // ---- pre-split embC + all weights ----
    {
        PSJobs J;
        const float* srcs[13] = {embC, WqC, WkC, WvC, Wk, Wv,
                                 Wq[0],Wq[1],Wq[2],Wq[3], Wo[0],Wo[1],Wo[2]};
        ushort* dsts[13] = {U(0),U(16),U(32),U(48),U(64),U(65),
                            U(66),U(67),U(68),U(69), U(70),U(71),U(72)};
        int blks[13] = {2048,2048,2048,2048,128,128, 128,128,128,128, 128,128,128};
        int a = 0;
        for (int j = 0; j < 13; ++j) { J.s[j]=srcs[j]; J.d[j]=dsts[j]; J.st[j]=a; a+=blks[j]; }
        J.st[13] = a;
        presplit<<<dim3(a), 256, 0, stream>>>(J);
    }
    // ---- channel projections: QCT/KCT transposed planes, VC natural planes ----
    gemm_ps<false,1><<<dim3(16, 4, 12), 256, 0, stream>>>(
        p4x(U(0)), p4x(U(16), U(32), U(48), U(48)), p4x(U(74), U(90), U(106), U(106)),
        i4x(TRC(512), TRC(512), 2048, 2048), nullptr, 2048, 4,
        1048576, 2048, 4194304,   0, 2048, 4194304,   1048576, 0, 4194304);
    // ---- pre-split emb1..4 (embC region dead) + Wo[3] ----
    {
        PSJobs J;
        const float* srcs[13] = {emb[0], emb[1], emb[2], emb[3], Wo[3],
                                 nullptr,nullptr,nullptr,nullptr,nullptr,nullptr,nullptr,nullptr};
        ushort* dsts[13] = {U(0), U(4), U(8), U(12), U(73),
                            nullptr,nullptr,nullptr,nullptr,nullptr,nullptr,nullptr,nullptr};
        int blks[5] = {512,512,512,512,128};
        int a = 0;
        for (int j = 0; j < 5; ++j) { J.s[j]=srcs[j]; J.d[j]=dsts[j]; J.st[j]=a; a+=blks[j]; }
        for (int j = 5; j < 14; ++j) J.st[j] = a;
        presplit<<<dim3(a), 256, 0, stream>>>(J);
    }
    // ---- attn_c over tokens (K=512) + stats -> fp16 scores ----
    gemm_ps<false,2><<<dim3(16, 16, 4), 256, 0, stream>>>(
        p4x(U(74)), p4x(U(90)), p4x(scores), i4x(0,0,0,0), stats, 512, 4,
        1048576, 512, 4194304,   1048576, 512, 4194304,   4194304, 2048, 0);
    softmax_rows<<<dim3(4*2048), 256, 0, stream>>>(scores, stats, 2048, 1.f/4194304.f);
    // ---- ctx_c = sim @ VC^T -> KVS planes (scatter) ----
    gemm_ps<true,3><<<dim3(4, 16, 4), 256, 0, stream>>>(
        p4x(scores), p4x(U(106)), p4x(U(48)), i4x(0,0,0,0), nullptr, 2048, 4,
        4194304, 2048, 0,   1048576, 2048, 4194304,   1048576, 0, 4194304);
    // ---- K = KVS@Wk^T (natural, ld 512); V = KVS@Wv^T (transposed VT, ld 2048) ----
    gemm_ps<false,1><<<dim3(4, 16, 8), 256, 0, stream>>>(
        p4x(U(48)), p4x(U(64), U(65), U(65), U(65)), p4x(U(74), U(90), U(90), U(90)),
        i4x(512, TRC(2048), 0, 0), nullptr, 512, 4,
        1048576, 512, 4194304,   0, 512, 262144,   1048576, 0, 4194304);
    // ---- Q projections (4 streams) -> Q planes ----
    gemm_ps<false,1><<<dim3(4, 4, 16), 256, 0, stream>>>(
        p4x(U(0), U(4), U(8), U(12)), p4x(U(66), U(67), U(68), U(69)),
        p4x(U(106), U(110), U(114), U(118)),
        i4x(512,512,512,512), nullptr, 512, 4,
        262144, 512, 1048576,   0, 512, 262144,   262144, 0, 1048576);
    // ---- Gram stats + finalize ----
    gram64<<<dim3(32, 8, 1), 256, 0, stream>>>(U(74), 4194304, GKp, 1048576, 0);
    gram64<<<dim3(32, 2, 4), 256, 0, stream>>>(U(106), 1048576, GQp, 262144, 2097152);
    fin_stats<<<dim3(32, 4), 256, 0, stream>>>(GQp, GKp, ssbuf);
    // ---- fused spatial attention -> ctx planes ----
    flash_ps<<<dim3(8, 32, 4), 256, 0, stream>>>(U(106), U(74), U(90), ssbuf, U(16));
    // ---- output projections -> d_out fp32 ----
    gemm_ps<false,0><<<dim3(4, 4, 16), 256, 0, stream>>>(
        p4x(U(16), U(20), U(24), U(28)), p4x(U(70), U(71), U(72), U(73)),
        p4x(out, out + 1048576, out + 2097152, out + 3145728),
        i4x(0,0,0,0), nullptr, 512, 4,
        262144, 512, 1048576,   0, 512, 262144,   262144, 512, 1048576);
}

// Round 5
// 708.453 us; speedup vs baseline: 5.5787x; 1.0436x over previous
//
#include <hip/hip_runtime.h>
#include <hip/hip_bf16.h>
#include <hip/hip_fp16.h>

typedef long long i64;
typedef unsigned int u32;
typedef __attribute__((ext_vector_type(8))) short bf16x8;
typedef __attribute__((ext_vector_type(4))) float f32x4;

#define MFMA_BF16 __builtin_amdgcn_mfma_f32_16x16x32_bf16

__device__ __forceinline__ void glds16(const void* g, void* l){
    __builtin_amdgcn_global_load_lds((const __attribute__((address_space(1))) u32*)g,
                                     (__attribute__((address_space(3))) u32*)l, 16, 0, 0);
}
// fp32 -> bf16 hi (truncate) + bf16 lo (residual). a ~= hi + lo, |err| ~ 2^-16 |a|
__device__ __forceinline__ void split1(float x, ushort& h, ushort& l){
    unsigned b = __float_as_uint(x);
    h = (ushort)(b >> 16);
    float hf = __uint_as_float(b & 0xFFFF0000u);
    float lf = x - hf;
    l = (ushort)(__float_as_uint(lf) >> 16);
}
__device__ __forceinline__ float bfpair(ushort h, ushort l){
    return __uint_as_float((u32)h << 16) + __uint_as_float((u32)l << 16);
}
__device__ __forceinline__ void ld4h(const __half* p, float v[4]){
    const __half2* q = (const __half2*)p;
    __half2 a = q[0], b = q[1];
    v[0]=__low2float(a); v[1]=__high2float(a);
    v[2]=__low2float(b); v[3]=__high2float(b);
}
// swizzled [64][64] bf16 tile read (flash): 16B-group g (0..7) XORed by row&7
__device__ __forceinline__ bf16x8 fragS(const ushort* P, int row, int g){
    return *(const bf16x8*)&P[row*64 + (((g) ^ (row & 7)) << 3)];
}

struct P4 { const void* p[4]; };
struct I4 { int v[4]; };

// ---------------- pre-split: fp32 -> bf16 hi/lo planes ----------------
struct PSJobs { const float* s[13]; ushort* d[13]; int st[14]; };
__global__ __launch_bounds__(256) void presplit(PSJobs J){
    int bid = blockIdx.x, j = 0;
    while (bid >= J.st[j+1]) ++j;
    i64 base = (i64)(bid - J.st[j])*2048 + threadIdx.x*8;
    i64 loOff = (i64)(J.st[j+1] - J.st[j])*2048;
    const float* sp = J.s[j]; ushort* dp = J.d[j];
    float4 a = *(const float4*)&sp[base];
    float4 b = *(const float4*)&sp[base+4];
    float v[8] = {a.x,a.y,a.z,a.w,b.x,b.y,b.z,b.w};
    ushort h[8], l[8];
    #pragma unroll
    for (int t = 0; t < 8; ++t) split1(v[t], h[t], l[t]);
    *(ushort4*)&dp[base]         = make_ushort4(h[0],h[1],h[2],h[3]);
    *(ushort4*)&dp[base+4]       = make_ushort4(h[4],h[5],h[6],h[7]);
    *(ushort4*)&dp[loOff+base]   = make_ushort4(l[0],l[1],l[2],l[3]);
    *(ushort4*)&dp[loOff+base+4] = make_ushort4(l[4],l[5],l[6],l[7]);
}

// ---------------- GEMM on pre-split planes, bf16x3, dbuf + stage-early + swizzle ----
// C[m,n] = sum_k A[m,k]*B[n,k]; A/B k-contiguous bf16 hi planes (lo at +aLo/+bLo).
// AF16: A is fp16 (reg-stage, exact split). OUT: 0 fp32; 1 bf16 planes, per-z1
// cfg = cmode.v[z1] = (transpose<<30)|cld; 2 fp16 + per-z stats; 3 KVS-scatter planes.
// LDS swizzle: data for k-group g of row r lives at group (g ^ ((r>>1)&3)); the
// global SOURCE is pre-swizzled (glds dest stays linear), reads apply the same XOR.
template<bool AF16, int OUT>
__global__ __launch_bounds__(256) void gemm_ps(
    P4 Ap, P4 Bp, P4 Cp, I4 cmode, float* __restrict__ stats,
    int K, int zdiv,
    i64 ab2, i64 alda, i64 aLo,
    i64 bb2, i64 bldb, i64 bLo,
    i64 cb2, i64 cld, i64 cLo)
{
    __shared__ ushort Ah[2][4096], Al[2][4096], Bh[2][4096], Bl[2][4096]; // [128][32]
    __shared__ float sred[4], qred[4];
    const int z = blockIdx.z, z1 = z / zdiv, z2 = z % zdiv;
    const int m0 = blockIdx.y*128, n0 = blockIdx.x*128;
    const int tid = threadIdx.x, lane = tid & 63, wid = tid >> 6;
    const int wm = wid >> 1, wn = wid & 1, fr = lane & 15, kc = lane >> 4;
    const ushort* Aps = (const ushort*)Ap.p[z1] + (i64)z2*ab2 + (i64)m0*alda;
    const __half* Af  = (const __half*)Ap.p[z1] + (i64)z2*ab2 + (i64)m0*alda;
    const ushort* Bps = (const ushort*)Bp.p[z1] + (i64)z2*bb2 + (i64)n0*bldb;

    const int srow = wid*32 + (lane >> 2);   // staging row (+ q*16)
    const int sg   = lane & 3;               // dest 16B-group within 64B row

    auto stageB = [&](int k0, int pb){
        #pragma unroll
        for (int q = 0; q < 2; ++q) {
            int r  = srow + q*16;
            int gs = sg ^ ((r >> 1) & 3);
            const ushort* sp = Bps + (i64)r*bldb + k0 + gs*8;
            glds16(sp,       &Bh[pb][(wid*32+q*16)*32]);
            glds16(sp + bLo, &Bl[pb][(wid*32+q*16)*32]);
        }
    };
    auto stageA = [&](int k0, int pb){
        if (!AF16) {
            #pragma unroll
            for (int q = 0; q < 2; ++q) {
                int r  = srow + q*16;
                int gs = sg ^ ((r >> 1) & 3);
                const ushort* sp = Aps + (i64)r*alda + k0 + gs*8;
                glds16(sp,       &Ah[pb][(wid*32+q*16)*32]);
                glds16(sp + aLo, &Al[pb][(wid*32+q*16)*32]);
            }
        } else {
            #pragma unroll
            for (int s4 = 0; s4 < 4; ++s4) {
                int v = tid + s4*256; int r = v >> 3, c4 = v & 7;
                float vals[4]; ld4h(&Af[(i64)r*alda + k0 + c4*4], vals);
                ushort h[4], l[4];
                #pragma unroll
                for (int t = 0; t < 4; ++t) split1(vals[t], h[t], l[t]);
                int pc = ((((c4 >> 1) ^ ((r >> 1) & 3)) << 1) | (c4 & 1)) * 4;
                *(ushort4*)&Ah[pb][r*32 + pc] = make_ushort4(h[0],h[1],h[2],h[3]);
                *(ushort4*)&Al[pb][r*32 + pc] = make_ushort4(l[0],l[1],l[2],l[3]);
            }
        }
    };
    auto rd = [&](const ushort* P, int row, int kcc)->bf16x8 {
        return *(const bf16x8*)&P[row*32 + ((kcc ^ ((row >> 1) & 3)) << 3)];
    };

    f32x4 acc[4][4];
    #pragma unroll
    for (int i = 0; i < 4; ++i)
        #pragma unroll
        for (int j = 0; j < 4; ++j) acc[i][j] = (f32x4){0.f,0.f,0.f,0.f};

    const int NT = K >> 5;
    stageA(0, 0); stageB(0, 0);
    __syncthreads();                               // tile 0 resident

    for (int t = 0; t < NT; ++t) {
        const int cur = t & 1;
        if (t + 1 < NT) {                          // prefetch next tile (flies under MFMA)
            stageA((t+1) << 5, cur ^ 1);
            stageB((t+1) << 5, cur ^ 1);
        }
        bf16x8 a_h[4], a_l[4], b_h[4], b_l[4];
        #pragma unroll
        for (int i = 0; i < 4; ++i) {
            int row = wm*64 + i*16 + fr;
            a_h[i] = rd(Ah[cur], row, kc);
            a_l[i] = rd(Al[cur], row, kc);
        }
        #pragma unroll
        for (int j = 0; j < 4; ++j) {
            int row = wn*64 + j*16 + fr;
            b_h[j] = rd(Bh[cur], row, kc);
            b_l[j] = rd(Bl[cur], row, kc);
        }
        #pragma unroll
        for (int i = 0; i < 4; ++i)
            #pragma unroll
            for (int j = 0; j < 4; ++j) {
                acc[i][j] = MFMA_BF16(a_h[i], b_h[j], acc[i][j], 0, 0, 0);
                acc[i][j] = MFMA_BF16(a_h[i], b_l[j], acc[i][j], 0, 0, 0);
                acc[i][j] = MFMA_BF16(a_l[i], b_h[j], acc[i][j], 0, 0, 0);
            }
        __syncthreads();                           // drain vmcnt+lgkm; swap buffers
    }

    const i64 cbase = (i64)z2*cb2;
    if (OUT == 0) {
        float* C = (float*)Cp.p[z1];
        #pragma unroll
        for (int i = 0; i < 4; ++i)
            #pragma unroll
            for (int j = 0; j < 4; ++j)
                #pragma unroll
                for (int r = 0; r < 4; ++r) {
                    int m = m0 + wm*64 + i*16 + kc*4 + r;
                    int n = n0 + wn*64 + j*16 + fr;
                    C[cbase + (i64)m*cld + n] = acc[i][j][r];
                }
    } else if (OUT == 1) {
        ushort* C = (ushort*)Cp.p[z1];
        const int cfg = cmode.v[z1];
        const int tr = cfg >> 30;
        const i64 ldv = cfg & 0x3FFFFFFF;
        #pragma unroll
        for (int i = 0; i < 4; ++i)
            #pragma unroll
            for (int j = 0; j < 4; ++j)
                #pragma unroll
                for (int r = 0; r < 4; ++r) {
                    int m = m0 + wm*64 + i*16 + kc*4 + r;
                    int n = n0 + wn*64 + j*16 + fr;
                    ushort h, l; split1(acc[i][j][r], h, l);
                    i64 off = cbase + (tr ? (i64)n*ldv + m : (i64)m*ldv + n);
                    C[off] = h; C[off + cLo] = l;
                }
    } else if (OUT == 2) {
        __half* C = (__half*)Cp.p[z1];
        float ls = 0.f, lq = 0.f;
        #pragma unroll
        for (int i = 0; i < 4; ++i)
            #pragma unroll
            for (int j = 0; j < 4; ++j)
                #pragma unroll
                for (int r = 0; r < 4; ++r) {
                    int m = m0 + wm*64 + i*16 + kc*4 + r;
                    int n = n0 + wn*64 + j*16 + fr;
                    float v = acc[i][j][r];
                    ls += v; lq += v*v;
                    C[cbase + (i64)m*cld + n] = __float2half(v);
                }
        #pragma unroll
        for (int off = 32; off; off >>= 1) { ls += __shfl_xor(ls, off); lq += __shfl_xor(lq, off); }
        if (lane == 0) { sred[wid] = ls; qred[wid] = lq; }
        __syncthreads();
        if (tid == 0) {
            atomicAdd(&stats[2*z],   sred[0]+sred[1]+sred[2]+sred[3]);
            atomicAdd(&stats[2*z+1], qred[0]+qred[1]+qred[2]+qred[3]);
        }
    } else {
        ushort* C = (ushort*)Cp.p[z1];
        #pragma unroll
        for (int i = 0; i < 4; ++i)
            #pragma unroll
            for (int j = 0; j < 4; ++j)
                #pragma unroll
                for (int r = 0; r < 4; ++r) {
                    int m = m0 + wm*64 + i*16 + kc*4 + r;
                    int n = n0 + wn*64 + j*16 + fr;
                    ushort h, l; split1(acc[i][j][r], h, l);
                    i64 off = cbase + ((i64)(m >> 9) << 18) + ((i64)n << 9) + (m & 511);
                    C[off] = h; C[off + cLo] = l;
                }
    }
}

// ---------------- channel softmax (fp16 in place) ----------------
__global__ __launch_bounds__(256) void softmax_rows(
    __half* __restrict__ attn, const float* __restrict__ stats,
    int rows_per_stat, float inv_count)
{
    const int ROWLEN = 2048;
    const int row = blockIdx.x;
    const int sidx = row / rows_per_stat;
    float sm = stats[2*sidx], sq = stats[2*sidx+1];
    float mean = sm * inv_count;
    float var = fmaxf(sq * inv_count - mean*mean, 0.f);
    float scale = rsqrtf(var + 1e-5f);
    __half* rp = attn + (i64)row * ROWLEN;
    const int tid = threadIdx.x;
    float v[8]; float mx = -3.4e38f;
    #pragma unroll
    for (int s = 0; s < 8; ++s) { float x = __half2float(rp[tid + s*256]) * scale; v[s] = x; mx = fmaxf(mx, x); }
    #pragma unroll
    for (int off = 32; off; off >>= 1) mx = fmaxf(mx, __shfl_xor(mx, off));
    __shared__ float red[4];
    if ((tid & 63) == 0) red[tid >> 6] = mx;
    __syncthreads();
    mx = fmaxf(fmaxf(red[0], red[1]), fmaxf(red[2], red[3]));
    float ls = 0.f;
    #pragma unroll
    for (int s = 0; s < 8; ++s) { float e = __expf(v[s] - mx); v[s] = e; ls += e; }
    #pragma unroll
    for (int off = 32; off; off >>= 1) ls += __shfl_xor(ls, off);
    __syncthreads();
    if ((tid & 63) == 0) red[tid >> 6] = ls;
    __syncthreads();
    float inv = 1.f / (red[0] + red[1] + red[2] + red[3]);
    #pragma unroll
    for (int s = 0; s < 8; ++s) rp[tid + s*256] = __float2half(v[s] * inv);
}

// ---------------- 64x64 Gram partials + column sums over 256 rows (planes input) ----------------
__global__ __launch_bounds__(256) void gram64(
    const ushort* __restrict__ hi, i64 loOff, float* __restrict__ parts,
    i64 bstride, i64 zs2)
{
    __shared__ float T[16][68];
    __shared__ float csred[4][64];
    const int z = blockIdx.x;
    const int tid = threadIdx.x;
    const ushort* base = hi + (i64)(z>>3)*bstride + (i64)blockIdx.z*zs2
                       + (i64)blockIdx.y*256*512 + (z&7)*64;
    float g[4][4] = {{0.f}};
    float cs = 0.f;
    const int sr = tid >> 4, sc = (tid & 15) * 4;
    const int col = tid & 63, qq = tid >> 6;
    for (int grp = 0; grp < 16; ++grp) {
        i64 idx = (i64)(grp*16 + sr)*512 + sc;
        ushort4 hv = *(const ushort4*)&base[idx];
        ushort4 lv = *(const ushort4*)&base[loOff + idx];
        float4 ld;
        ld.x = bfpair(hv.x, lv.x); ld.y = bfpair(hv.y, lv.y);
        ld.z = bfpair(hv.z, lv.z); ld.w = bfpair(hv.w, lv.w);
        __syncthreads();
        *(float4*)&T[sr][sc] = ld;
        __syncthreads();
        #pragma unroll
        for (int rr = 0; rr < 16; ++rr) {
            const float4 a = *(const float4*)&T[rr][sr*4];
            const float4 b = *(const float4*)&T[rr][sc];
            g[0][0]+=a.x*b.x; g[0][1]+=a.x*b.y; g[0][2]+=a.x*b.z; g[0][3]+=a.x*b.w;
            g[1][0]+=a.y*b.x; g[1][1]+=a.y*b.y; g[1][2]+=a.y*b.z; g[1][3]+=a.y*b.w;
            g[2][0]+=a.z*b.x; g[2][1]+=a.z*b.y; g[2][2]+=a.z*b.z; g[2][3]+=a.z*b.w;
            g[3][0]+=a.w*b.x; g[3][1]+=a.w*b.y; g[3][2]+=a.w*b.z; g[3][3]+=a.w*b.w;
        }
        cs += T[qq*4+0][col] + T[qq*4+1][col] + T[qq*4+2][col] + T[qq*4+3][col];
    }
    float* outp = parts + (i64)((blockIdx.z*gridDim.y + blockIdx.y)*gridDim.x + blockIdx.x)*4160;
    #pragma unroll
    for (int x = 0; x < 4; ++x)
        #pragma unroll
        for (int y = 0; y < 4; ++y)
            outp[(sr*4+x)*64 + sc + y] = g[x][y];
    csred[qq][col] = cs;
    __syncthreads();
    if (tid < 64) outp[4096 + tid] = csred[0][tid]+csred[1][tid]+csred[2][tid]+csred[3][tid];
}

// scale/shift per (s,z): S1 = qbar.kbar, S2 = <G_Q, G_K>_F
__global__ __launch_bounds__(256) void fin_stats(
    const float* __restrict__ gq, const float* __restrict__ gk,
    float* __restrict__ ss)
{
    const int z = blockIdx.x, s = blockIdx.y;
    const int tid = threadIdx.x;
    const int lane = tid & 63, wid = tid >> 6;
    const float* q0 = gq + (i64)((s*2+0)*32 + z)*4160;
    const float* q1 = gq + (i64)((s*2+1)*32 + z)*4160;
    float p2 = 0.f;
    for (int i = tid; i < 4096; i += 256) {
        float a = q0[i] + q1[i];
        float b = 0.f;
        #pragma unroll
        for (int c = 0; c < 8; ++c) b += gk[(i64)(c*32 + z)*4160 + i];
        p2 += a*b;
    }
    float p1 = 0.f;
    if (tid < 64) {
        float a = q0[4096+tid] + q1[4096+tid];
        float b = 0.f;
        #pragma unroll
        for (int c = 0; c < 8; ++c) b += gk[(i64)(c*32 + z)*4160 + 4096 + tid];
        p1 = a*b;
    }
    #pragma unroll
    for (int off = 32; off; off >>= 1) { p2 += __shfl_xor(p2, off); p1 += __shfl_xor(p1, off); }
    __shared__ float r2[4], r1[4];
    if (lane == 0) { r2[wid] = p2; r1[wid] = p1; }
    __syncthreads();
    if (tid == 0) {
        float S2 = r2[0]+r2[1]+r2[2]+r2[3];
        float S1 = r1[0]+r1[1]+r1[2]+r1[3];
        const float inv = 1.f/1048576.f;
        float mu = S1*inv;
        float var = fmaxf(S2*inv - mu*mu, 0.f);
        float sc = rsqrtf(var + 1e-5f);
        ss[(s*32+z)*2] = sc;
        ss[(s*32+z)*2+1] = sc*mu;
    }
}

// ---------------- fused spatial flash attention on planes ----------------
__global__ __launch_bounds__(256) void flash_ps(
    const ushort* __restrict__ Qp, const ushort* __restrict__ Kp,
    const ushort* __restrict__ Vtp, const float* __restrict__ ss,
    ushort* __restrict__ ctxp)
{
    __shared__ ushort QPh[4096], QPl[4096];        // Q in prologue, P in loop
    __shared__ ushort Kh[4096], Kl[4096];
    __shared__ ushort Vh[2][4096], Vl[2][4096];
    __shared__ float denl[2][64];
    const int qt = blockIdx.x, zz = blockIdx.y, s = blockIdx.z;
    const int b = zz >> 3, hD = (zz & 7) * 64;
    const float scale = ss[(s*32+zz)*2], shift = ss[(s*32+zz)*2+1];
    const ushort* Qb = Qp + (i64)s*2097152 + (i64)b*262144 + (i64)(qt*64)*512 + hD;
    const ushort* Kb = Kp + (i64)b*1048576 + hD;
    const ushort* Vb = Vtp + (i64)b*1048576 + (i64)hD*2048;
    const int tid = threadIdx.x, lane = tid & 63, wid = tid >> 6;
    const int wq = wid >> 1, wk = wid & 1, fr = lane & 15, kc = lane >> 4;

    auto stage64 = [&](const ushort* src, i64 ld, i64 lo, ushort* Lh, ushort* Ll){
        #pragma unroll
        for (int q = 0; q < 2; ++q) {
            int rb = wid*16 + q*8;
            int r = rb + (lane >> 3);
            int gs = (lane & 7) ^ (r & 7);
            const ushort* p = src + (i64)r*ld + gs*8;
            glds16(p,      &Lh[rb*64]);
            glds16(p + lo, &Ll[rb*64]);
        }
    };

    stage64(Qb, 512, 1048576, QPh, QPl);
    stage64(Kb, 512, 4194304, Kh, Kl);
    stage64(Vb, 2048, 4194304, Vh[0], Vl[0]);
    __syncthreads();                       // Q, K0, V0 resident

    bf16x8 qh[2][2], ql[2][2];
    #pragma unroll
    for (int i = 0; i < 2; ++i)
        #pragma unroll
        for (int ks = 0; ks < 2; ++ks) {
            int row = wq*32 + i*16 + fr;
            qh[i][ks] = fragS(QPh, row, ks*4 + kc);
            ql[i][ks] = fragS(QPl, row, ks*4 + kc);
        }
    __syncthreads();                       // all Q hoists done before P overwrites

    f32x4 ctx[2][2];
    #pragma unroll
    for (int i = 0; i < 2; ++i)
        #pragma unroll
        for (int j = 0; j < 2; ++j) ctx[i][j] = (f32x4){0.f,0.f,0.f,0.f};
    float den_lr[2][4] = {{0.f}};

    for (int t = 0; t < 32; ++t) {
        f32x4 sacc[2][2];
        #pragma unroll
        for (int i = 0; i < 2; ++i)
            #pragma unroll
            for (int j = 0; j < 2; ++j) sacc[i][j] = (f32x4){0.f,0.f,0.f,0.f};
        #pragma unroll
        for (int ks = 0; ks < 2; ++ks) {
            bf16x8 khf[2], klf[2];
            #pragma unroll
            for (int j = 0; j < 2; ++j) {
                int row = wk*32 + j*16 + fr;
                khf[j] = fragS(Kh, row, ks*4 + kc);
                klf[j] = fragS(Kl, row, ks*4 + kc);
            }
            #pragma unroll
            for (int i = 0; i < 2; ++i)
                #pragma unroll
                for (int j = 0; j < 2; ++j) {
                    sacc[i][j] = MFMA_BF16(qh[i][ks], khf[j], sacc[i][j], 0, 0, 0);
                    sacc[i][j] = MFMA_BF16(qh[i][ks], klf[j], sacc[i][j], 0, 0, 0);
                    sacc[i][j] = MFMA_BF16(ql[i][ks], khf[j], sacc[i][j], 0, 0, 0);
                }
        }
        // P = exp(scale*s - shift); den accumulate; swizzled store to QP region
        #pragma unroll
        for (int i = 0; i < 2; ++i)
            #pragma unroll
            for (int j = 0; j < 2; ++j)
                #pragma unroll
                for (int r = 0; r < 4; ++r) {
                    float p = __expf(sacc[i][j][r]*scale - shift);
                    den_lr[i][r] += p;
                    ushort h, l; split1(p, h, l);
                    int row = wq*32 + i*16 + kc*4 + r;
                    int col = wk*32 + j*16 + fr;
                    int pos = row*64 + ((((col>>3) ^ (row&7)) << 3) | (col & 7));
                    QPh[pos] = h; QPl[pos] = l;
                }
        __syncthreads();                   // P visible; all K(t) reads done
        if (t + 1 < 32) {                  // prefetch flies under PV
            stage64(Kb + (i64)((t+1)*64)*512, 512, 4194304, Kh, Kl);
            stage64(Vb + (t+1)*64, 2048, 4194304, Vh[(t+1)&1], Vl[(t+1)&1]);
        }
        #pragma unroll
        for (int ks = 0; ks < 2; ++ks) {
            bf16x8 vhf[2], vlf[2], pah[2], pal[2];
            #pragma unroll
            for (int j = 0; j < 2; ++j) {
                int row = wk*32 + j*16 + fr;
                vhf[j] = fragS(Vh[t&1], row, ks*4 + kc);
                vlf[j] = fragS(Vl[t&1], row, ks*4 + kc);
            }
            #pragma unroll
            for (int i = 0; i < 2; ++i) {
                int row = wq*32 + i*16 + fr;
                pah[i] = fragS(QPh, row, ks*4 + kc);
                pal[i] = fragS(QPl, row, ks*4 + kc);
            }
            #pragma unroll
            for (int i = 0; i < 2; ++i)
                #pragma unroll
                for (int j = 0; j < 2; ++j) {
                    ctx[i][j] = MFMA_BF16(pah[i], vhf[j], ctx[i][j], 0, 0, 0);
                    ctx[i][j] = MFMA_BF16(pah[i], vlf[j], ctx[i][j], 0, 0, 0);
                    ctx[i][j] = MFMA_BF16(pal[i], vhf[j], ctx[i][j], 0, 0, 0);
                }
        }
        __syncthreads();                   // PV reads done; drain makes K/V(t+1) resident
    }

    #pragma unroll
    for (int i = 0; i < 2; ++i)
        #pragma unroll
        for (int r = 0; r < 4; ++r) {
            float d = den_lr[i][r];
            d += __shfl_xor(d, 1); d += __shfl_xor(d, 2);
            d += __shfl_xor(d, 4); d += __shfl_xor(d, 8);
            if (fr == 0) denl[wk][wq*32 + i*16 + kc*4 + r] = d;
        }
    __syncthreads();
    ushort* Cb = ctxp + (i64)s*2097152 + (i64)b*262144;
    #pragma unroll
    for (int i = 0; i < 2; ++i)
        #pragma unroll
        for (int j = 0; j < 2; ++j)
            #pragma unroll
            for (int r = 0; r < 4; ++r) {
                int row = wq*32 + i*16 + kc*4 + r;
                int col = wk*32 + j*16 + fr;
                float dv = denl[0][row] + denl[1][row];
                ushort h, l; split1(ctx[i][j][r] / dv, h, l);
                i64 off = (i64)(qt*64 + row)*512 + hD + col;
                Cb[off] = h; Cb[off + 1048576] = l;
            }
}

static inline P4 p4x(const void* a, const void* b, const void* c, const void* d){
    P4 x; x.p[0]=a; x.p[1]=b; x.p[2]=c; x.p[3]=d; return x;
}
static inline P4 p4x(const void* a){ return p4x(a,a,a,a); }
static inline I4 i4x(int a, int b, int c, int d){ I4 x; x.v[0]=a; x.v[1]=b; x.v[2]=c; x.v[3]=d; return x; }
#define TRC(ld) ((1<<30)|(ld))   // transposed plane store with leading dim ld

extern "C" void kernel_launch(void* const* d_in, const int* in_sizes, int n_in,
                              void* d_out, int out_size, void* d_ws, size_t ws_size,
                              hipStream_t stream)
{
    (void)in_sizes; (void)n_in; (void)out_size;
    const float* emb[4] = {(const float*)d_in[0], (const float*)d_in[1],
                           (const float*)d_in[2], (const float*)d_in[3]};
    const float* embC = (const float*)d_in[4];
    const float* Wq[4] = {(const float*)d_in[5], (const float*)d_in[6],
                          (const float*)d_in[7], (const float*)d_in[8]};
    const float* Wk  = (const float*)d_in[9];
    const float* Wv  = (const float*)d_in[10];
    const float* WqC = (const float*)d_in[11];
    const float* WkC = (const float*)d_in[12];
    const float* WvC = (const float*)d_in[13];
    const float* Wo[4] = {(const float*)d_in[14], (const float*)d_in[15],
                          (const float*)d_in[16], (const float*)d_in[17]};
    float* out = (float*)d_out;

    char* ws = (char*)d_ws;
    const size_t MB = 1024*1024;
    if (ws_size < 128*MB + 512) return;
    auto U = [&](size_t mb){ return (ushort*)(ws + mb*MB); };
    // layout (MB): 0..16 embC planes -> emb planes | 16..48 WqC/WkC planes -> scores -> ctx planes
    // 48..64 WvC planes -> KVS planes -> gram parts | 64..74 small W planes
    // 74..90 QCT -> K planes | 90..106 KCT -> VT planes | 106..122 VC -> Q planes | 122..128 stats
    float* stats = (float*)(ws + 122*MB);
    float* ssbuf = (float*)(ws + 122*MB + 1024);
    float* GKp   = (float*)(ws + 48*MB);
    float* GQp   = (float*)(ws + 53*MB);
    __half* scores = (__half*)(ws + 16*MB);

    hipMemsetAsync(stats, 0, 512, stream);

    // ---- pre-split embC + all weights ----
    {
        PSJobs J;
        const float* srcs[13] = {embC, WqC, WkC, WvC, Wk, Wv,
                                 Wq[0],Wq[1],Wq[2],Wq[3], Wo[0],Wo[1],Wo[2]};
        ushort* dsts[13] = {U(0),U(16),U(32),U(48),U(64),U(65),
                            U(66),U(67),U(68),U(69), U(70),U(71),U(72)};
        int blks[13] = {2048,2048,2048,2048,128,128, 128,128,128,128, 128,128,128};
        int a = 0;
        for (int j = 0; j < 13; ++j) { J.s[j]=srcs[j]; J.d[j]=dsts[j]; J.st[j]=a; a+=blks[j]; }
        J.st[13] = a;
        presplit<<<dim3(a), 256, 0, stream>>>(J);
    }
    // ---- channel projections: QCT/KCT transposed planes, VC natural planes ----
    gemm_ps<false,1><<<dim3(16, 4, 12), 256, 0, stream>>>(
        p4x(U(0)), p4x(U(16), U(32), U(48), U(48)), p4x(U(74), U(90), U(106), U(106)),
        i4x(TRC(512), TRC(512), 2048, 2048), nullptr, 2048, 4,
        1048576, 2048, 4194304,   0, 2048, 4194304,   1048576, 0, 4194304);
    // ---- pre-split emb1..4 (embC region dead) + Wo[3] ----
    {
        PSJobs J;
        const float* srcs[13] = {emb[0], emb[1], emb[2], emb[3], Wo[3],
                                 nullptr,nullptr,nullptr,nullptr,nullptr,nullptr,nullptr,nullptr};
        ushort* dsts[13] = {U(0), U(4), U(8), U(12), U(73),
                            nullptr,nullptr,nullptr,nullptr,nullptr,nullptr,nullptr,nullptr};
        int blks[5] = {512,512,512,512,128};
        int a = 0;
        for (int j = 0; j < 5; ++j) { J.s[j]=srcs[j]; J.d[j]=dsts[j]; J.st[j]=a; a+=blks[j]; }
        for (int j = 5; j < 14; ++j) J.st[j] = a;
        presplit<<<dim3(a), 256, 0, stream>>>(J);
    }
    // ---- attn_c over tokens (K=512) + stats -> fp16 scores ----
    gemm_ps<false,2><<<dim3(16, 16, 4), 256, 0, stream>>>(
        p4x(U(74)), p4x(U(90)), p4x(scores), i4x(0,0,0,0), stats, 512, 4,
        1048576, 512, 4194304,   1048576, 512, 4194304,   4194304, 2048, 0);
    softmax_rows<<<dim3(4*2048), 256, 0, stream>>>(scores, stats, 2048, 1.f/4194304.f);
    // ---- ctx_c = sim @ VC^T -> KVS planes (scatter) ----
    gemm_ps<true,3><<<dim3(4, 16, 4), 256, 0, stream>>>(
        p4x(scores), p4x(U(106)), p4x(U(48)), i4x(0,0,0,0), nullptr, 2048, 4,
        4194304, 2048, 0,   1048576, 2048, 4194304,   1048576, 0, 4194304);
    // ---- K = KVS@Wk^T (natural, ld 512); V = KVS@Wv^T (transposed VT, ld 2048) ----
    gemm_ps<false,1><<<dim3(4, 16, 8), 256, 0, stream>>>(
        p4x(U(48)), p4x(U(64), U(65), U(65), U(65)), p4x(U(74), U(90), U(90), U(90)),
        i4x(512, TRC(2048), 0, 0), nullptr, 512, 4,
        1048576, 512, 4194304,   0, 512, 262144,   1048576, 0, 4194304);
    // ---- Q projections (4 streams) -> Q planes ----
    gemm_ps<false,1><<<dim3(4, 4, 16), 256, 0, stream>>>(
        p4x(U(0), U(4), U(8), U(12)), p4x(U(66), U(67), U(68), U(69)),
        p4x(U(106), U(110), U(114), U(118)),
        i4x(512,512,512,512), nullptr, 512, 4,
        262144, 512, 1048576,   0, 512, 262144,   262144, 0, 1048576);
    // ---- Gram stats + finalize ----
    gram64<<<dim3(32, 8, 1), 256, 0, stream>>>(U(74), 4194304, GKp, 1048576, 0);
    gram64<<<dim3(32, 2, 4), 256, 0, stream>>>(U(106), 1048576, GQp, 262144, 2097152);
    fin_stats<<<dim3(32, 4), 256, 0, stream>>>(GQp, GKp, ssbuf);
    // ---- fused spatial attention -> ctx planes ----
    flash_ps<<<dim3(8, 32, 4), 256, 0, stream>>>(U(106), U(74), U(90), ssbuf, U(16));
    // ---- output projections -> d_out fp32 ----
    gemm_ps<false,0><<<dim3(4, 4, 16), 256, 0, stream>>>(
        p4x(U(16), U(20), U(24), U(28)), p4x(U(70), U(71), U(72), U(73)),
        p4x(out, out + 1048576, out + 2097152, out + 3145728),
        i4x(0,0,0,0), nullptr, 512, 4,
        262144, 512, 1048576,   0, 512, 262144,   262144, 512, 1048576);
}

// Round 6
// 672.734 us; speedup vs baseline: 5.8749x; 1.0531x over previous
//
#include <hip/hip_runtime.h>
#include <hip/hip_bf16.h>
#include <hip/hip_fp16.h>

typedef long long i64;
typedef unsigned int u32;
typedef __attribute__((ext_vector_type(8))) short bf16x8;
typedef __attribute__((ext_vector_type(4))) float f32x4;

#define MFMA_BF16 __builtin_amdgcn_mfma_f32_16x16x32_bf16
#define VMCNT(n)  asm volatile("s_waitcnt vmcnt(" #n ")" ::: "memory")
#define LGKM0     asm volatile("s_waitcnt lgkmcnt(0)" ::: "memory")
#define SBAR      __builtin_amdgcn_s_barrier()
#define SCHED0    __builtin_amdgcn_sched_barrier(0)

__device__ __forceinline__ void glds16(const void* g, void* l){
    __builtin_amdgcn_global_load_lds((const __attribute__((address_space(1))) u32*)g,
                                     (__attribute__((address_space(3))) u32*)l, 16, 0, 0);
}
// fp32 -> bf16 hi (truncate) + bf16 lo (residual). a ~= hi + lo, |err| ~ 2^-16 |a|
__device__ __forceinline__ void split1(float x, ushort& h, ushort& l){
    unsigned b = __float_as_uint(x);
    h = (ushort)(b >> 16);
    float hf = __uint_as_float(b & 0xFFFF0000u);
    float lf = x - hf;
    l = (ushort)(__float_as_uint(lf) >> 16);
}
__device__ __forceinline__ float bfpair(ushort h, ushort l){
    return __uint_as_float((u32)h << 16) + __uint_as_float((u32)l << 16);
}
// swizzled [64][64] bf16 tile read (flash): 16B-group g (0..7) XORed by row&7
__device__ __forceinline__ bf16x8 fragS(const ushort* P, int row, int g){
    return *(const bf16x8*)&P[row*64 + (((g) ^ (row & 7)) << 3)];
}

struct P4 { const void* p[4]; };
struct I4 { int v[4]; };

// ---------------- pre-split: fp32 -> bf16 hi/lo planes ----------------
struct PSJobs { const float* s[13]; ushort* d[13]; int st[14]; };
__global__ __launch_bounds__(256) void presplit(PSJobs J){
    int bid = blockIdx.x, j = 0;
    while (bid >= J.st[j+1]) ++j;
    i64 base = (i64)(bid - J.st[j])*2048 + threadIdx.x*8;
    i64 loOff = (i64)(J.st[j+1] - J.st[j])*2048;
    const float* sp = J.s[j]; ushort* dp = J.d[j];
    float4 a = *(const float4*)&sp[base];
    float4 b = *(const float4*)&sp[base+4];
    float v[8] = {a.x,a.y,a.z,a.w,b.x,b.y,b.z,b.w};
    ushort h[8], l[8];
    #pragma unroll
    for (int t = 0; t < 8; ++t) split1(v[t], h[t], l[t]);
    *(ushort4*)&dp[base]         = make_ushort4(h[0],h[1],h[2],h[3]);
    *(ushort4*)&dp[base+4]       = make_ushort4(h[4],h[5],h[6],h[7]);
    *(ushort4*)&dp[loOff+base]   = make_ushort4(l[0],l[1],l[2],l[3]);
    *(ushort4*)&dp[loOff+base+4] = make_ushort4(l[4],l[5],l[6],l[7]);
}

// ---------------- GEMM on pre-split planes, bf16x3, counted-vmcnt pipeline ----
// C[m,n] = sum_k A[m,k]*B[n,k]; A/B k-contiguous bf16 hi planes (lo at +aLo/+bLo).
// OUT: 0 fp32; 1 bf16 planes, per-z1 cfg = (transpose<<30)|cld; 2 fp16 + stats;
// 3 KVS-scatter planes.
// Pipeline: 2 LDS buffers, stage tile t+2 after reads-done barrier, vmcnt(8)
// (8 glds/wave/tile) -- loads get ~2 iterations of flight, never drained mid-loop.
template<int OUT>
__global__ __launch_bounds__(256) void gemm_ps(
    P4 Ap, P4 Bp, P4 Cp, I4 cmode, float* __restrict__ stats,
    int K, int zdiv,
    i64 ab2, i64 alda, i64 aLo,
    i64 bb2, i64 bldb, i64 bLo,
    i64 cb2, i64 cld, i64 cLo)
{
    __shared__ ushort Ah[2][4096], Al[2][4096], Bh[2][4096], Bl[2][4096]; // [128][32]
    __shared__ float sred[4], qred[4];
    const int z = blockIdx.z, z1 = z / zdiv, z2 = z % zdiv;
    const int m0 = blockIdx.y*128, n0 = blockIdx.x*128;
    const int tid = threadIdx.x, lane = tid & 63, wid = tid >> 6;
    const int wm = wid >> 1, wn = wid & 1, fr = lane & 15, kc = lane >> 4;
    const ushort* Aps = (const ushort*)Ap.p[z1] + (i64)z2*ab2 + (i64)m0*alda;
    const ushort* Bps = (const ushort*)Bp.p[z1] + (i64)z2*bb2 + (i64)n0*bldb;

    const int srow = wid*32 + (lane >> 2);   // staging row (+ q*16)
    const int sg   = lane & 3;               // dest 16B-group within 64B row

    auto stageAB = [&](int k0, int pb){      // 8 glds/wave
        #pragma unroll
        for (int q = 0; q < 2; ++q) {
            int r  = srow + q*16;
            int gs = sg ^ ((r >> 1) & 3);
            const ushort* sa = Aps + (i64)r*alda + k0 + gs*8;
            glds16(sa,       &Ah[pb][(wid*32+q*16)*32]);
            glds16(sa + aLo, &Al[pb][(wid*32+q*16)*32]);
            const ushort* sb = Bps + (i64)r*bldb + k0 + gs*8;
            glds16(sb,       &Bh[pb][(wid*32+q*16)*32]);
            glds16(sb + bLo, &Bl[pb][(wid*32+q*16)*32]);
        }
    };
    auto rd = [&](const ushort* P, int row, int kcc)->bf16x8 {
        return *(const bf16x8*)&P[row*32 + ((kcc ^ ((row >> 1) & 3)) << 3)];
    };

    f32x4 acc[4][4];
    #pragma unroll
    for (int i = 0; i < 4; ++i)
        #pragma unroll
        for (int j = 0; j < 4; ++j) acc[i][j] = (f32x4){0.f,0.f,0.f,0.f};

    const int NT = K >> 5;
    stageAB(0, 0); stageAB(32, 1);                 // 16 loads in flight

    for (int t = 0; t < NT; ++t) {
        const int cur = t & 1;
        if (t + 1 < NT) { VMCNT(8); } else { VMCNT(0); }   // tile t resident
        SBAR;
        bf16x8 a_h[4], a_l[4], b_h[4], b_l[4];
        #pragma unroll
        for (int i = 0; i < 4; ++i) {
            int row = wm*64 + i*16 + fr;
            a_h[i] = rd(Ah[cur], row, kc);
            a_l[i] = rd(Al[cur], row, kc);
        }
        #pragma unroll
        for (int j = 0; j < 4; ++j) {
            int row = wn*64 + j*16 + fr;
            b_h[j] = rd(Bh[cur], row, kc);
            b_l[j] = rd(Bl[cur], row, kc);
        }
        __builtin_amdgcn_s_setprio(1);
        #pragma unroll
        for (int i = 0; i < 4; ++i)
            #pragma unroll
            for (int j = 0; j < 4; ++j) {
                acc[i][j] = MFMA_BF16(a_h[i], b_h[j], acc[i][j], 0, 0, 0);
                acc[i][j] = MFMA_BF16(a_h[i], b_l[j], acc[i][j], 0, 0, 0);
                acc[i][j] = MFMA_BF16(a_l[i], b_h[j], acc[i][j], 0, 0, 0);
            }
        __builtin_amdgcn_s_setprio(0);
        LGKM0;                                     // all reads of buf[cur] done
        SBAR;
        SCHED0;
        if (t + 2 < NT) stageAB((t+2) << 5, cur);  // overwrite freed buffer
    }

    const i64 cbase = (i64)z2*cb2;
    if (OUT == 0) {
        float* C = (float*)Cp.p[z1];
        #pragma unroll
        for (int i = 0; i < 4; ++i)
            #pragma unroll
            for (int j = 0; j < 4; ++j)
                #pragma unroll
                for (int r = 0; r < 4; ++r) {
                    int m = m0 + wm*64 + i*16 + kc*4 + r;
                    int n = n0 + wn*64 + j*16 + fr;
                    C[cbase + (i64)m*cld + n] = acc[i][j][r];
                }
    } else if (OUT == 1) {
        ushort* C = (ushort*)Cp.p[z1];
        const int cfg = cmode.v[z1];
        const int tr = cfg >> 30;
        const i64 ldv = cfg & 0x3FFFFFFF;
        #pragma unroll
        for (int i = 0; i < 4; ++i)
            #pragma unroll
            for (int j = 0; j < 4; ++j)
                #pragma unroll
                for (int r = 0; r < 4; ++r) {
                    int m = m0 + wm*64 + i*16 + kc*4 + r;
                    int n = n0 + wn*64 + j*16 + fr;
                    ushort h, l; split1(acc[i][j][r], h, l);
                    i64 off = cbase + (tr ? (i64)n*ldv + m : (i64)m*ldv + n);
                    C[off] = h; C[off + cLo] = l;
                }
    } else if (OUT == 2) {
        __half* C = (__half*)Cp.p[z1];
        float ls = 0.f, lq = 0.f;
        #pragma unroll
        for (int i = 0; i < 4; ++i)
            #pragma unroll
            for (int j = 0; j < 4; ++j)
                #pragma unroll
                for (int r = 0; r < 4; ++r) {
                    int m = m0 + wm*64 + i*16 + kc*4 + r;
                    int n = n0 + wn*64 + j*16 + fr;
                    float v = acc[i][j][r];
                    ls += v; lq += v*v;
                    C[cbase + (i64)m*cld + n] = __float2half(v);
                }
        #pragma unroll
        for (int off = 32; off; off >>= 1) { ls += __shfl_xor(ls, off); lq += __shfl_xor(lq, off); }
        if (lane == 0) { sred[wid] = ls; qred[wid] = lq; }
        __syncthreads();
        if (tid == 0) {
            atomicAdd(&stats[2*z],   sred[0]+sred[1]+sred[2]+sred[3]);
            atomicAdd(&stats[2*z+1], qred[0]+qred[1]+qred[2]+qred[3]);
        }
    } else {
        ushort* C = (ushort*)Cp.p[z1];
        #pragma unroll
        for (int i = 0; i < 4; ++i)
            #pragma unroll
            for (int j = 0; j < 4; ++j)
                #pragma unroll
                for (int r = 0; r < 4; ++r) {
                    int m = m0 + wm*64 + i*16 + kc*4 + r;
                    int n = n0 + wn*64 + j*16 + fr;
                    ushort h, l; split1(acc[i][j][r], h, l);
                    i64 off = cbase + ((i64)(m >> 9) << 18) + ((i64)n << 9) + (m & 511);
                    C[off] = h; C[off + cLo] = l;
                }
    }
}

// ---------------- channel softmax: fp16 scores in -> sim bf16 hi/lo planes out ----
__global__ __launch_bounds__(256) void softmax_rows(
    __half* __restrict__ attn, ushort* __restrict__ lo,
    const float* __restrict__ stats, int rows_per_stat, float inv_count)
{
    const int ROWLEN = 2048;
    const int row = blockIdx.x;
    const int sidx = row / rows_per_stat;
    float sm = stats[2*sidx], sq = stats[2*sidx+1];
    float mean = sm * inv_count;
    float var = fmaxf(sq * inv_count - mean*mean, 0.f);
    float scale = rsqrtf(var + 1e-5f);
    __half* rp = attn + (i64)row * ROWLEN;
    ushort* hp = (ushort*)rp;                 // hi plane written in place
    ushort* lp = lo + (i64)row * ROWLEN;
    const int tid = threadIdx.x;
    float v[8]; float mx = -3.4e38f;
    #pragma unroll
    for (int s = 0; s < 8; ++s) { float x = __half2float(rp[tid + s*256]) * scale; v[s] = x; mx = fmaxf(mx, x); }
    #pragma unroll
    for (int off = 32; off; off >>= 1) mx = fmaxf(mx, __shfl_xor(mx, off));
    __shared__ float red[4];
    if ((tid & 63) == 0) red[tid >> 6] = mx;
    __syncthreads();
    mx = fmaxf(fmaxf(red[0], red[1]), fmaxf(red[2], red[3]));
    float ls = 0.f;
    #pragma unroll
    for (int s = 0; s < 8; ++s) { float e = __expf(v[s] - mx); v[s] = e; ls += e; }
    #pragma unroll
    for (int off = 32; off; off >>= 1) ls += __shfl_xor(ls, off);
    __syncthreads();
    if ((tid & 63) == 0) red[tid >> 6] = ls;
    __syncthreads();
    float inv = 1.f / (red[0] + red[1] + red[2] + red[3]);
    #pragma unroll
    for (int s = 0; s < 8; ++s) {
        ushort h, l; split1(v[s] * inv, h, l);
        hp[tid + s*256] = h; lp[tid + s*256] = l;
    }
}

// ---------------- 64x64 Gram partials + column sums over 256 rows (planes input) ----------------
__global__ __launch_bounds__(256) void gram64(
    const ushort* __restrict__ hi, i64 loOff, float* __restrict__ parts,
    i64 bstride, i64 zs2)
{
    __shared__ float T[16][68];
    __shared__ float csred[4][64];
    const int z = blockIdx.x;
    const int tid = threadIdx.x;
    const ushort* base = hi + (i64)(z>>3)*bstride + (i64)blockIdx.z*zs2
                       + (i64)blockIdx.y*256*512 + (z&7)*64;
    float g[4][4] = {{0.f}};
    float cs = 0.f;
    const int sr = tid >> 4, sc = (tid & 15) * 4;
    const int col = tid & 63, qq = tid >> 6;
    for (int grp = 0; grp < 16; ++grp) {
        i64 idx = (i64)(grp*16 + sr)*512 + sc;
        ushort4 hv = *(const ushort4*)&base[idx];
        ushort4 lv = *(const ushort4*)&base[loOff + idx];
        float4 ld;
        ld.x = bfpair(hv.x, lv.x); ld.y = bfpair(hv.y, lv.y);
        ld.z = bfpair(hv.z, lv.z); ld.w = bfpair(hv.w, lv.w);
        __syncthreads();
        *(float4*)&T[sr][sc] = ld;
        __syncthreads();
        #pragma unroll
        for (int rr = 0; rr < 16; ++rr) {
            const float4 a = *(const float4*)&T[rr][sr*4];
            const float4 b = *(const float4*)&T[rr][sc];
            g[0][0]+=a.x*b.x; g[0][1]+=a.x*b.y; g[0][2]+=a.x*b.z; g[0][3]+=a.x*b.w;
            g[1][0]+=a.y*b.x; g[1][1]+=a.y*b.y; g[1][2]+=a.y*b.z; g[1][3]+=a.y*b.w;
            g[2][0]+=a.z*b.x; g[2][1]+=a.z*b.y; g[2][2]+=a.z*b.z; g[2][3]+=a.z*b.w;
            g[3][0]+=a.w*b.x; g[3][1]+=a.w*b.y; g[3][2]+=a.w*b.z; g[3][3]+=a.w*b.w;
        }
        cs += T[qq*4+0][col] + T[qq*4+1][col] + T[qq*4+2][col] + T[qq*4+3][col];
    }
    float* outp = parts + (i64)((blockIdx.z*gridDim.y + blockIdx.y)*gridDim.x + blockIdx.x)*4160;
    #pragma unroll
    for (int x = 0; x < 4; ++x)
        #pragma unroll
        for (int y = 0; y < 4; ++y)
            outp[(sr*4+x)*64 + sc + y] = g[x][y];
    csred[qq][col] = cs;
    __syncthreads();
    if (tid < 64) outp[4096 + tid] = csred[0][tid]+csred[1][tid]+csred[2][tid]+csred[3][tid];
}

// scale/shift per (s,z): S1 = qbar.kbar, S2 = <G_Q, G_K>_F
__global__ __launch_bounds__(256) void fin_stats(
    const float* __restrict__ gq, const float* __restrict__ gk,
    float* __restrict__ ss)
{
    const int z = blockIdx.x, s = blockIdx.y;
    const int tid = threadIdx.x;
    const int lane = tid & 63, wid = tid >> 6;
    const float* q0 = gq + (i64)((s*2+0)*32 + z)*4160;
    const float* q1 = gq + (i64)((s*2+1)*32 + z)*4160;
    float p2 = 0.f;
    for (int i = tid; i < 4096; i += 256) {
        float a = q0[i] + q1[i];
        float b = 0.f;
        #pragma unroll
        for (int c = 0; c < 8; ++c) b += gk[(i64)(c*32 + z)*4160 + i];
        p2 += a*b;
    }
    float p1 = 0.f;
    if (tid < 64) {
        float a = q0[4096+tid] + q1[4096+tid];
        float b = 0.f;
        #pragma unroll
        for (int c = 0; c < 8; ++c) b += gk[(i64)(c*32 + z)*4160 + 4096 + tid];
        p1 = a*b;
    }
    #pragma unroll
    for (int off = 32; off; off >>= 1) { p2 += __shfl_xor(p2, off); p1 += __shfl_xor(p1, off); }
    __shared__ float r2[4], r1[4];
    if (lane == 0) { r2[wid] = p2; r1[wid] = p1; }
    __syncthreads();
    if (tid == 0) {
        float S2 = r2[0]+r2[1]+r2[2]+r2[3];
        float S1 = r1[0]+r1[1]+r1[2]+r1[3];
        const float inv = 1.f/1048576.f;
        float mu = S1*inv;
        float var = fmaxf(S2*inv - mu*mu, 0.f);
        float sc = rsqrtf(var + 1e-5f);
        ss[(s*32+z)*2] = sc;
        ss[(s*32+z)*2+1] = sc*mu;
    }
}

// ---------------- fused spatial flash attention, counted-vmcnt pipeline ----------------
__global__ __launch_bounds__(256) void flash_ps(
    const ushort* __restrict__ Qp, const ushort* __restrict__ Kp,
    const ushort* __restrict__ Vtp, const float* __restrict__ ss,
    ushort* __restrict__ ctxp)
{
    __shared__ ushort QPh[4096], QPl[4096];        // Q in prologue, P in loop (16KB)
    __shared__ ushort Kh[2][4096], Kl[2][4096];    // 32KB
    __shared__ ushort Vh[2][4096], Vl[2][4096];    // 32KB   (total 80KB -> 2 blocks/CU)
    const int qt = blockIdx.x, zz = blockIdx.y, s = blockIdx.z;
    const int b = zz >> 3, hD = (zz & 7) * 64;
    const float scale = ss[(s*32+zz)*2], shift = ss[(s*32+zz)*2+1];
    const ushort* Qb = Qp + (i64)s*2097152 + (i64)b*262144 + (i64)(qt*64)*512 + hD;
    const ushort* Kb = Kp + (i64)b*1048576 + hD;
    const ushort* Vb = Vtp + (i64)b*1048576 + (i64)hD*2048;
    const int tid = threadIdx.x, lane = tid & 63, wid = tid >> 6;
    const int wq = wid >> 1, wk = wid & 1, fr = lane & 15, kc = lane >> 4;

    auto stage64 = [&](const ushort* src, i64 ld, i64 lo, ushort* Lh, ushort* Ll){
        #pragma unroll
        for (int q = 0; q < 2; ++q) {           // 4 glds/wave
            int rb = wid*16 + q*8;
            int r = rb + (lane >> 3);
            int gs = (lane & 7) ^ (r & 7);
            const ushort* p = src + (i64)r*ld + gs*8;
            glds16(p,      &Lh[rb*64]);
            glds16(p + lo, &Ll[rb*64]);
        }
    };

    stage64(Qb, 512, 1048576, QPh, QPl);           // 4
    stage64(Kb, 512, 4194304, Kh[0], Kl[0]);       // 8
    stage64(Vb, 2048, 4194304, Vh[0], Vl[0]);      // 12 in flight
    VMCNT(8); SBAR;                                // Q resident
    bf16x8 qh[2][2], ql[2][2];
    #pragma unroll
    for (int i = 0; i < 2; ++i)
        #pragma unroll
        for (int ks = 0; ks < 2; ++ks) {
            int row = wq*32 + i*16 + fr;
            qh[i][ks] = fragS(QPh, row, ks*4 + kc);
            ql[i][ks] = fragS(QPl, row, ks*4 + kc);
        }
    LGKM0; SBAR;                                   // Q hoisted; QP free for P
    SCHED0;
    stage64(Kb + (i64)64*512, 512, 4194304, Kh[1], Kl[1]);
    stage64(Vb + 64, 2048, 4194304, Vh[1], Vl[1]); // 16 in flight (K0,V0,K1,V1)

    f32x4 ctx[2][2];
    #pragma unroll
    for (int i = 0; i < 2; ++i)
        #pragma unroll
        for (int j = 0; j < 2; ++j) ctx[i][j] = (f32x4){0.f,0.f,0.f,0.f};
    float den_lr[2][4] = {{0.f}};

    for (int t = 0; t < 32; ++t) {
        const int cur = t & 1;
        if (t < 31) { VMCNT(8); } else { VMCNT(0); }   // K(t),V(t) resident
        SBAR;
        // ---- QK^T ----
        f32x4 sacc[2][2];
        #pragma unroll
        for (int i = 0; i < 2; ++i)
            #pragma unroll
            for (int j = 0; j < 2; ++j) sacc[i][j] = (f32x4){0.f,0.f,0.f,0.f};
        #pragma unroll
        for (int ks = 0; ks < 2; ++ks) {
            bf16x8 khf[2], klf[2];
            #pragma unroll
            for (int j = 0; j < 2; ++j) {
                int row = wk*32 + j*16 + fr;
                khf[j] = fragS(Kh[cur], row, ks*4 + kc);
                klf[j] = fragS(Kl[cur], row, ks*4 + kc);
            }
            __builtin_amdgcn_s_setprio(1);
            #pragma unroll
            for (int i = 0; i < 2; ++i)
                #pragma unroll
                for (int j = 0; j < 2; ++j) {
                    sacc[i][j] = MFMA_BF16(qh[i][ks], khf[j], sacc[i][j], 0, 0, 0);
                    sacc[i][j] = MFMA_BF16(qh[i][ks], klf[j], sacc[i][j], 0, 0, 0);
                    sacc[i][j] = MFMA_BF16(ql[i][ks], khf[j], sacc[i][j], 0, 0, 0);
                }
            __builtin_amdgcn_s_setprio(0);
        }
        // ---- P = exp(scale*s - shift); den; swizzled store ----
        #pragma unroll
        for (int i = 0; i < 2; ++i)
            #pragma unroll
            for (int j = 0; j < 2; ++j)
                #pragma unroll
                for (int r = 0; r < 4; ++r) {
                    float p = __expf(sacc[i][j][r]*scale - shift);
                    den_lr[i][r] += p;
                    ushort h, l; split1(p, h, l);
                    int row = wq*32 + i*16 + kc*4 + r;
                    int col = wk*32 + j*16 + fr;
                    int pos = row*64 + ((((col>>3) ^ (row&7)) << 3) | (col & 7));
                    QPh[pos] = h; QPl[pos] = l;
                }
        LGKM0; SBAR;                           // P visible; K[cur] reads done
        SCHED0;
        if (t < 30) stage64(Kb + (i64)((t+2)*64)*512, 512, 4194304, Kh[cur], Kl[cur]);
        // ---- ctx += P V ----
        #pragma unroll
        for (int ks = 0; ks < 2; ++ks) {
            bf16x8 vhf[2], vlf[2], pah[2], pal[2];
            #pragma unroll
            for (int j = 0; j < 2; ++j) {
                int row = wk*32 + j*16 + fr;
                vhf[j] = fragS(Vh[cur], row, ks*4 + kc);
                vlf[j] = fragS(Vl[cur], row, ks*4 + kc);
            }
            #pragma unroll
            for (int i = 0; i < 2; ++i) {
                int row = wq*32 + i*16 + fr;
                pah[i] = fragS(QPh, row, ks*4 + kc);
                pal[i] = fragS(QPl, row, ks*4 + kc);
            }
            __builtin_amdgcn_s_setprio(1);
            #pragma unroll
            for (int i = 0; i < 2; ++i)
                #pragma unroll
                for (int j = 0; j < 2; ++j) {
                    ctx[i][j] = MFMA_BF16(pah[i], vhf[j], ctx[i][j], 0, 0, 0);
                    ctx[i][j] = MFMA_BF16(pah[i], vlf[j], ctx[i][j], 0, 0, 0);
                    ctx[i][j] = MFMA_BF16(pal[i], vhf[j], ctx[i][j], 0, 0, 0);
                }
            __builtin_amdgcn_s_setprio(0);
        }
        LGKM0; SBAR;                           // V[cur]+P reads done
        SCHED0;
        if (t < 30) stage64(Vb + (t+2)*64, 2048, 4194304, Vh[cur], Vl[cur]);
    }

    // epilogue: den reduce (overlay float scratch on QPl; all P reads complete)
    float* denf = (float*)QPl;
    #pragma unroll
    for (int i = 0; i < 2; ++i)
        #pragma unroll
        for (int r = 0; r < 4; ++r) {
            float d = den_lr[i][r];
            d += __shfl_xor(d, 1); d += __shfl_xor(d, 2);
            d += __shfl_xor(d, 4); d += __shfl_xor(d, 8);
            if (fr == 0) denf[wk*64 + wq*32 + i*16 + kc*4 + r] = d;
        }
    __syncthreads();
    ushort* Cb = ctxp + (i64)s*2097152 + (i64)b*262144;
    #pragma unroll
    for (int i = 0; i < 2; ++i)
        #pragma unroll
        for (int j = 0; j < 2; ++j)
            #pragma unroll
            for (int r = 0; r < 4; ++r) {
                int row = wq*32 + i*16 + kc*4 + r;
                int col = wk*32 + j*16 + fr;
                float dv = denf[row] + denf[64 + row];
                ushort h, l; split1(ctx[i][j][r] / dv, h, l);
                i64 off = (i64)(qt*64 + row)*512 + hD + col;
                Cb[off] = h; Cb[off + 1048576] = l;
            }
}

static inline P4 p4x(const void* a, const void* b, const void* c, const void* d){
    P4 x; x.p[0]=a; x.p[1]=b; x.p[2]=c; x.p[3]=d; return x;
}
static inline P4 p4x(const void* a){ return p4x(a,a,a,a); }
static inline I4 i4x(int a, int b, int c, int d){ I4 x; x.v[0]=a; x.v[1]=b; x.v[2]=c; x.v[3]=d; return x; }
#define TRC(ld) ((1<<30)|(ld))   // transposed plane store with leading dim ld

extern "C" void kernel_launch(void* const* d_in, const int* in_sizes, int n_in,
                              void* d_out, int out_size, void* d_ws, size_t ws_size,
                              hipStream_t stream)
{
    (void)in_sizes; (void)n_in; (void)out_size;
    const float* emb[4] = {(const float*)d_in[0], (const float*)d_in[1],
                           (const float*)d_in[2], (const float*)d_in[3]};
    const float* embC = (const float*)d_in[4];
    const float* Wq[4] = {(const float*)d_in[5], (const float*)d_in[6],
                          (const float*)d_in[7], (const float*)d_in[8]};
    const float* Wk  = (const float*)d_in[9];
    const float* Wv  = (const float*)d_in[10];
    const float* WqC = (const float*)d_in[11];
    const float* WkC = (const float*)d_in[12];
    const float* WvC = (const float*)d_in[13];
    const float* Wo[4] = {(const float*)d_in[14], (const float*)d_in[15],
                          (const float*)d_in[16], (const float*)d_in[17]};
    float* out = (float*)d_out;

    char* ws = (char*)d_ws;
    const size_t MB = 1024*1024;
    if (ws_size < 128*MB + 512) return;
    auto U = [&](size_t mb){ return (ushort*)(ws + mb*MB); };
    // layout (MB): 0..16 embC planes -> emb planes | 16..48 WqC/WkC planes -> scores/sim-hi -> ctx planes
    // 48..64 WvC planes -> KVS planes -> gram parts | 64..74 small W planes
    // 74..90 QCT -> sim-lo -> K planes | 90..106 KCT -> sim-lo -> VT planes
    // 106..122 VC -> Q planes | 122..128 stats
    float* stats = (float*)(ws + 122*MB);
    float* ssbuf = (float*)(ws + 122*MB + 1024);
    float* GKp   = (float*)(ws + 48*MB);
    float* GQp   = (float*)(ws + 53*MB);
    __half* scores = (__half*)(ws + 16*MB);

    hipMemsetAsync(stats, 0, 512, stream);

    // ---- pre-split embC + all weights ----
    {
        PSJobs J;
        const float* srcs[13] = {embC, WqC, WkC, WvC, Wk, Wv,
                                 Wq[0],Wq[1],Wq[2],Wq[3], Wo[0],Wo[1],Wo[2]};
        ushort* dsts[13] = {U(0),U(16),U(32),U(48),U(64),U(65),
                            U(66),U(67),U(68),U(69), U(70),U(71),U(72)};
        int blks[13] = {2048,2048,2048,2048,128,128, 128,128,128,128, 128,128,128};
        int a = 0;
        for (int j = 0; j < 13; ++j) { J.s[j]=srcs[j]; J.d[j]=dsts[j]; J.st[j]=a; a+=blks[j]; }
        J.st[13] = a;
        presplit<<<dim3(a), 256, 0, stream>>>(J);
    }
    // ---- channel projections: QCT/KCT transposed planes, VC natural planes ----
    gemm_ps<1><<<dim3(16, 4, 12), 256, 0, stream>>>(
        p4x(U(0)), p4x(U(16), U(32), U(48), U(48)), p4x(U(74), U(90), U(106), U(106)),
        i4x(TRC(512), TRC(512), 2048, 2048), nullptr, 2048, 4,
        1048576, 2048, 4194304,   0, 2048, 4194304,   1048576, 0, 4194304);
    // ---- pre-split emb1..4 (embC region dead) + Wo[3] ----
    {
        PSJobs J;
        const float* srcs[13] = {emb[0], emb[1], emb[2], emb[3], Wo[3],
                                 nullptr,nullptr,nullptr,nullptr,nullptr,nullptr,nullptr,nullptr};
        ushort* dsts[13] = {U(0), U(4), U(8), U(12), U(73),
                            nullptr,nullptr,nullptr,nullptr,nullptr,nullptr,nullptr,nullptr};
        int blks[5] = {512,512,512,512,128};
        int a = 0;
        for (int j = 0; j < 5; ++j) { J.s[j]=srcs[j]; J.d[j]=dsts[j]; J.st[j]=a; a+=blks[j]; }
        for (int j = 5; j < 14; ++j) J.st[j] = a;
        presplit<<<dim3(a), 256, 0, stream>>>(J);
    }
    // ---- attn_c over tokens (K=512) + stats -> fp16 scores ----
    gemm_ps<2><<<dim3(16, 16, 4), 256, 0, stream>>>(
        p4x(U(74)), p4x(U(90)), p4x(scores), i4x(0,0,0,0), stats, 512, 4,
        1048576, 512, 4194304,   1048576, 512, 4194304,   4194304, 2048, 0);
    // ---- softmax: scores -> sim planes (hi in place at U(16), lo at U(74)) ----
    softmax_rows<<<dim3(4*2048), 256, 0, stream>>>(scores, U(74), stats, 2048, 1.f/4194304.f);
    // ---- ctx_c = sim @ VC^T -> KVS planes (scatter); sim-lo 58MB above hi ----
    gemm_ps<3><<<dim3(4, 16, 4), 256, 0, stream>>>(
        p4x(U(16)), p4x(U(106)), p4x(U(48)), i4x(0,0,0,0), nullptr, 2048, 4,
        4194304, 2048, 30408704,   1048576, 2048, 4194304,   1048576, 0, 4194304);
    // ---- K = KVS@Wk^T (natural, ld 512); V = KVS@Wv^T (transposed VT, ld 2048) ----
    gemm_ps<1><<<dim3(4, 16, 8), 256, 0, stream>>>(
        p4x(U(48)), p4x(U(64), U(65), U(65), U(65)), p4x(U(74), U(90), U(90), U(90)),
        i4x(512, TRC(2048), 0, 0), nullptr, 512, 4,
        1048576, 512, 4194304,   0, 512, 262144,   1048576, 0, 4194304);
    // ---- Q projections (4 streams) -> Q planes ----
    gemm_ps<1><<<dim3(4, 4, 16), 256, 0, stream>>>(
        p4x(U(0), U(4), U(8), U(12)), p4x(U(66), U(67), U(68), U(69)),
        p4x(U(106), U(110), U(114), U(118)),
        i4x(512,512,512,512), nullptr, 512, 4,
        262144, 512, 1048576,   0, 512, 262144,   262144, 0, 1048576);
    // ---- Gram stats + finalize ----
    gram64<<<dim3(32, 8, 1), 256, 0, stream>>>(U(74), 4194304, GKp, 1048576, 0);
    gram64<<<dim3(32, 2, 4), 256, 0, stream>>>(U(106), 1048576, GQp, 262144, 2097152);
    fin_stats<<<dim3(32, 4), 256, 0, stream>>>(GQp, GKp, ssbuf);
    // ---- fused spatial attention -> ctx planes ----
    flash_ps<<<dim3(8, 32, 4), 256, 0, stream>>>(U(106), U(74), U(90), ssbuf, U(16));
    // ---- output projections -> d_out fp32 ----
    gemm_ps<0><<<dim3(4, 4, 16), 256, 0, stream>>>(
        p4x(U(16), U(20), U(24), U(28)), p4x(U(70), U(71), U(72), U(73)),
        p4x(out, out + 1048576, out + 2097152, out + 3145728),
        i4x(0,0,0,0), nullptr, 512, 4,
        262144, 512, 1048576,   0, 512, 262144,   262144, 512, 1048576);
}